// Round 4
// baseline (555.419 us; speedup 1.0000x reference)
//
#include <hip/hip_runtime.h>
#include <stdint.h>

typedef __bf16 bf16x8 __attribute__((ext_vector_type(8)));
typedef __bf16 bf16x4 __attribute__((ext_vector_type(4)));
typedef float  f32x4  __attribute__((ext_vector_type(4)));

// ================== fused prologue: packall + x0->bf16 cvt + bhist(L1) + bhist(L2) ====
__device__ __forceinline__ void d_pack(int o,
    const float* W1a, const float* R1a, const float* W2a, const float* R2a,
    const float* W1b, const float* R1b, const float* W2b, const float* R2b,
    __bf16* BpA, __bf16* BpB, __bf16* BpC, __bf16* BpD) {
  const float *W, *R; __bf16* Bp; int Cin, Cout;
  if (o < 20480)      { W = W1a; R = R1a; Bp = BpA; Cin = 64; Cout = 32; }
  else if (o < 30720) { W = W2a; R = R2a; Bp = BpB; Cin = 32; Cout = 32; o -= 20480; }
  else if (o < 35840) { W = W1b; R = R1b; Bp = BpC; Cin = 32; Cout = 16; o -= 30720; }
  else if (o < 38400) { W = W2b; R = R2b; Bp = BpD; Cin = 16; Cout = 16; o -= 35840; }
  else return;
  int CT = Cout / 16;
  int j = o & 7, lane = (o >> 3) & 63, tile = o >> 9;
  int ct = tile % CT, kc = tile / CT;
  int k = kc * 32 + ((lane >> 4) * 8) + j;
  int n = ct * 16 + (lane & 15);
  float v;
  if (k < 9 * Cin) { int k9 = k / Cin, cin = k - k9 * Cin; v = W[(k9 * Cin + cin) * Cout + n]; }
  else             { v = R[(k - 9 * Cin) * Cout + n]; }
  Bp[o] = (__bf16)v;
}

__device__ __forceinline__ void d_bhist(int b, int t, const int* dst, int E,
                                        int* bcnt, int nbk) {
  __shared__ int h[256];
  h[t] = 0;
  __syncthreads();
  int e0 = b * 2048 + t * 8;
  if (e0 + 8 <= E) {
    int4 a = *reinterpret_cast<const int4*>(dst + e0);
    int4 c = *reinterpret_cast<const int4*>(dst + e0 + 4);
    atomicAdd(&h[a.x >> 10], 1); atomicAdd(&h[a.y >> 10], 1);
    atomicAdd(&h[a.z >> 10], 1); atomicAdd(&h[a.w >> 10], 1);
    atomicAdd(&h[c.x >> 10], 1); atomicAdd(&h[c.y >> 10], 1);
    atomicAdd(&h[c.z >> 10], 1); atomicAdd(&h[c.w >> 10], 1);
  } else {
    for (int j = 0; j < 8; ++j)
      if (e0 + j < E) atomicAdd(&h[dst[e0 + j] >> 10], 1);
  }
  __syncthreads();
  if (t < nbk && h[t]) atomicAdd(&bcnt[t], h[t]);
}

__global__ __launch_bounds__(256) void k_prologue(
    const float* __restrict__ W1a, const float* __restrict__ R1a,
    const float* __restrict__ W2a, const float* __restrict__ R2a,
    const float* __restrict__ W1b, const float* __restrict__ R1b,
    const float* __restrict__ W2b, const float* __restrict__ R2b,
    __bf16* __restrict__ BpA, __bf16* __restrict__ BpB,
    __bf16* __restrict__ BpC, __bf16* __restrict__ BpD,
    const float4* __restrict__ x0, __bf16* __restrict__ x0bf,
    const int* __restrict__ dst1, int E1, int* __restrict__ bcnt1, int nbk1,
    const int* __restrict__ dst2, int E2, int* __restrict__ bcnt2, int nbk2) {
  int b = blockIdx.x, t = threadIdx.x;
  if (b < 150) {
    d_pack(b * 256 + t, W1a, R1a, W2a, R2a, W1b, R1b, W2b, R2b, BpA, BpB, BpC, BpD);
  } else if (b < 775) {
    int i = (b - 150) * 256 + t;            // N0*16 = 160,000 float4 items
    if (i < 160000) {
      float4 v = x0[i];
      bf16x4 o = {(__bf16)v.x, (__bf16)v.y, (__bf16)v.z, (__bf16)v.w};
      *reinterpret_cast<bf16x4*>(x0bf + (size_t)i * 4) = o;
    }
  } else if (b < 893) {
    d_bhist(b - 775, t, dst1, E1, bcnt1, nbk1);
  } else {
    d_bhist(b - 893, t, dst2, E2, bcnt2, nbk2);
  }
}

// ---------------- dual bucket scan: block 0 = L1, block 1 = L2 ----------------
__global__ void k_bscan_dual(const int* __restrict__ bcnt1, int nbk1, int E1,
                             int* __restrict__ bstart1, int* __restrict__ bcur1,
                             const int* __restrict__ bcnt2, int nbk2, int E2,
                             int* __restrict__ bstart2, int* __restrict__ bcur2) {
  const int* bcnt; int nbk, E; int *bstart, *bcur;
  if (blockIdx.x == 0) { bcnt = bcnt1; nbk = nbk1; E = E1; bstart = bstart1; bcur = bcur1; }
  else                 { bcnt = bcnt2; nbk = nbk2; E = E2; bstart = bstart2; bcur = bcur2; }
  __shared__ int wsum[4];
  int t = threadIdx.x, lane = t & 63, w = t >> 6;
  int v = (t < nbk) ? bcnt[t] : 0;
  int x = v;
  #pragma unroll
  for (int o = 1; o < 64; o <<= 1) { int y = __shfl_up(x, o, 64); if (lane >= o) x += y; }
  if (lane == 63) wsum[w] = x;
  __syncthreads();
  int wpre = 0;
  #pragma unroll
  for (int k = 0; k < 4; ++k) if (k < w) wpre += wsum[k];
  int excl = wpre + x - v;
  if (t < nbk) { bstart[t] = excl; bcur[t] = excl; }
  if (t == 0) bstart[nbk] = E;
}

// ---------------- dual partition: blocks [0,118) L1, [118,587) L2 ----------------
__device__ __forceinline__ void d_bpart(int b, int t, const int* src, const int* dst,
                                        const float2* pse, const int* up, int E, int* bcur,
                                        uint2* ebuf, uint16_t* rbuf, int nbk) {
  __shared__ int h[256];
  __shared__ int base[256];
  h[t] = 0;
  __syncthreads();
  int e0 = b * 2048 + t * 8;
  int d[8], rank[8];
  bool full = (e0 + 8 <= E);
  if (full) {
    int4 a = *reinterpret_cast<const int4*>(dst + e0);
    int4 c = *reinterpret_cast<const int4*>(dst + e0 + 4);
    d[0] = a.x; d[1] = a.y; d[2] = a.z; d[3] = a.w;
    d[4] = c.x; d[5] = c.y; d[6] = c.z; d[7] = c.w;
    #pragma unroll
    for (int j = 0; j < 8; ++j) rank[j] = atomicAdd(&h[d[j] >> 10], 1);
  } else {
    #pragma unroll
    for (int j = 0; j < 8; ++j)
      if (e0 + j < E) { d[j] = dst[e0 + j]; rank[j] = atomicAdd(&h[d[j] >> 10], 1); }
  }
  __syncthreads();
  if (t < nbk && h[t]) base[t] = atomicAdd(&bcur[t], h[t]);
  __syncthreads();
  if (full) {
    int4 a = *reinterpret_cast<const int4*>(src + e0);
    int4 c = *reinterpret_cast<const int4*>(src + e0 + 4);
    int s[8] = {a.x, a.y, a.z, a.w, c.x, c.y, c.z, c.w};
    int u[8];
    #pragma unroll
    for (int j = 0; j < 8; ++j) u[j] = up[s[j]];
    float2 p[8];
    #pragma unroll
    for (int j = 0; j < 8; ++j) p[j] = pse[e0 + j];
    #pragma unroll
    for (int j = 0; j < 8; ++j) {
      int bkt = d[j] >> 10, dloc = d[j] & 1023;
      union { uint uu; _Float16 hh[2]; } cv;
      cv.hh[0] = (_Float16)p[j].x; cv.hh[1] = (_Float16)p[j].y;
      int pos = base[bkt] + rank[j];
      ebuf[pos] = make_uint2((uint)s[j] | ((uint)dloc << 18), cv.uu);
      rbuf[pos] = (uint16_t)u[j];
    }
  } else {
    #pragma unroll
    for (int j = 0; j < 8; ++j) {
      if (e0 + j >= E) continue;
      int bkt = d[j] >> 10, dloc = d[j] & 1023;
      int sj = src[e0 + j];
      float2 p = pse[e0 + j];
      union { uint uu; _Float16 hh[2]; } cv;
      cv.hh[0] = (_Float16)p.x; cv.hh[1] = (_Float16)p.y;
      int pos = base[bkt] + rank[j];
      ebuf[pos] = make_uint2((uint)sj | ((uint)dloc << 18), cv.uu);
      rbuf[pos] = (uint16_t)up[sj];
    }
  }
}

__global__ __launch_bounds__(256) void k_bpart_dual(
    const int* __restrict__ src1, const int* __restrict__ dst1, const float2* __restrict__ pse1,
    const int* __restrict__ up1, int E1, int* __restrict__ bcur1,
    uint2* __restrict__ ebuf1, uint16_t* __restrict__ rbuf1, int nbk1, int NB1,
    const int* __restrict__ src2, const int* __restrict__ dst2, const float2* __restrict__ pse2,
    const int* __restrict__ up2, int E2, int* __restrict__ bcur2,
    uint2* __restrict__ ebuf2, uint16_t* __restrict__ rbuf2, int nbk2) {
  int b = blockIdx.x, t = threadIdx.x;
  if (b < NB1) d_bpart(b, t, src1, dst1, pse1, up1, E1, bcur1, ebuf1, rbuf1, nbk1);
  else         d_bpart(b - NB1, t, src2, dst2, pse2, up2, E2, bcur2, ebuf2, rbuf2, nbk2);
}

// ---------------- dual per-bucket CSR finalize: blocks [0,40) L1, [40,197) L2 ----------
__device__ __forceinline__ void d_bcsr(int b, int t, const int* bstart, const uint2* ebuf,
                                       const uint16_t* rbuf, uint2* epk, uint2* epkR,
                                       int* off, int N, int E, int nbk) {
  __shared__ int cnt[1024];
  __shared__ int excl[1024];
  __shared__ int cur[1024];
  __shared__ int wsum[4];
  int e0 = bstart[b], e1 = bstart[b + 1];
  #pragma unroll
  for (int k = 0; k < 4; ++k) { cnt[t * 4 + k] = 0; cur[t * 4 + k] = 0; }
  __syncthreads();
  for (int i = e0 + t; i < e1; i += 256)
    atomicAdd(&cnt[(ebuf[i].x >> 18) & 1023], 1);
  __syncthreads();
  int lane = t & 63, w = t >> 6;
  int i0 = t * 4;
  int c0 = cnt[i0], c1 = cnt[i0 + 1], c2 = cnt[i0 + 2], c3 = cnt[i0 + 3];
  int s = c0 + c1 + c2 + c3, x = s;
  #pragma unroll
  for (int o = 1; o < 64; o <<= 1) { int y = __shfl_up(x, o, 64); if (lane >= o) x += y; }
  if (lane == 63) wsum[w] = x;
  __syncthreads();
  int wpre = 0;
  #pragma unroll
  for (int k = 0; k < 4; ++k) if (k < w) wpre += wsum[k];
  int ex = wpre + x - s;
  excl[i0] = ex; excl[i0 + 1] = ex + c0; excl[i0 + 2] = ex + c0 + c1; excl[i0 + 3] = ex + c0 + c1 + c2;
  int dg0 = b * 1024;
  int exv[4] = {ex, ex + c0, ex + c0 + c1, ex + c0 + c1 + c2};
  #pragma unroll
  for (int k = 0; k < 4; ++k) {
    int d = dg0 + i0 + k;
    if (d < N) off[d] = e0 + exv[k];
  }
  __syncthreads();
  for (int i = e0 + t; i < e1; i += 256) {
    uint2 r = ebuf[i];
    uint rs = rbuf[i];
    int dloc = (r.x >> 18) & 1023;
    int rk = atomicAdd(&cur[dloc], 1);
    int pos = e0 + excl[dloc] + rk;
    epk[pos]  = make_uint2(r.x & 0x3FFFFu, r.y);
    epkR[pos] = make_uint2(rs, r.y);
  }
  if (b == nbk - 1 && t == 0) off[N] = E;
}

__global__ __launch_bounds__(256) void k_bcsr_dual(
    const int* __restrict__ bstart1, const uint2* __restrict__ ebuf1,
    const uint16_t* __restrict__ rbuf1, uint2* __restrict__ epk1, uint2* __restrict__ epkR1,
    int* __restrict__ off1, int N1, int E1, int nbk1,
    const int* __restrict__ bstart2, const uint2* __restrict__ ebuf2,
    const uint16_t* __restrict__ rbuf2, uint2* __restrict__ epk2, uint2* __restrict__ epkR2,
    int* __restrict__ off2, int N2, int E2, int nbk2) {
  int b = blockIdx.x, t = threadIdx.x;
  if (b < nbk1) d_bcsr(b, t, bstart1, ebuf1, rbuf1, epk1, epkR1, off1, N1, E1, nbk1);
  else          d_bcsr(b - nbk1, t, bstart2, ebuf2, rbuf2, epk2, epkR2, off2, N2, E2, nbk2);
}

// ---- per-edge spline accumulate (4 channels/thread); msk=0 makes it an exact no-op ----
__device__ __forceinline__ void edge1(uint ps, const bf16x4 xf, float msk, float (&acc)[9][4]) {
  union { uint u; _Float16 h[2]; } cv; cv.u = ps;
  float t0 = (float)cv.h[0], t1 = (float)cv.h[1];
  float u0 = 1.f - t0;
  float wi[3] = {msk * 0.5f * u0 * u0, msk * (-t0 * t0 + t0 + 0.5f), msk * 0.5f * t0 * t0};
  float u1 = 1.f - t1;
  float wj[3] = {0.5f * u1 * u1, -t1 * t1 + t1 + 0.5f, 0.5f * t1 * t1};
  float xfv[4];
  #pragma unroll
  for (int v = 0; v < 4; ++v) xfv[v] = (float)xf[v];
  #pragma unroll
  for (int ki = 0; ki < 3; ++ki)
    #pragma unroll
    for (int kj = 0; kj < 3; ++kj) {
      float w = wi[ki] * wj[kj];
      #pragma unroll
      for (int v = 0; v < 4; ++v)
        acc[ki * 3 + kj][v] += w * xfv[v];
    }
}

// -------- fused spline conv: SW-pipelined chunk-4 edge loop + masked chunk-3 tail -----
// R14: R13's mask-everything regressed (+33% issued work for -33% rounds; work term
// dominates). This version adds NO work to full chunks: A/B double-buffered chunk state
// overlaps chunk n+1's epk+gather latency under chunk n's VALU (pure ILP), and the tail
// (0-3 edges) issues as ONE masked 3-wide round instead of 1-3 serial scalar rounds
// (+0.5 edges/dst avg). Cin=64 path = R1 verbatim (chunk4 + scalar tail, no pipeline).
// (256,4): cap 128 VGPR -- pipeline needs ~80, spill-proof (R12 lesson). Spill signature
// to watch: conv WRITE_SIZE >> output size.
template<int Cin, int Cout, bool OUTF32, bool HAS_SKIP, bool REMAP>
__global__ __launch_bounds__(256, 4) void k_conv(
                        const int* __restrict__ off,
                        const uint2* __restrict__ epk,
                        const __bf16* __restrict__ X, const __bf16* __restrict__ Bp,
                        const float* __restrict__ bias, const float* __restrict__ skip,
                        const int* __restrict__ up,
                        void* __restrict__ outv, int N, int outStride) {
  constexpr int LPD = Cin / 4;      // lanes per dst: 4/8/16
  constexpr int DPB = 256 / LPD;    // dsts per block: 64/32/16
  constexpr int K   = 10 * Cin;     // 160/320/640
  constexpr int KP2 = K + 8;        // LDS row stride
  constexpr int NT  = DPB / 16;     // MFMA row-tiles per block
  constexpr int KC  = K / 32;
  constexpr int CT  = Cout / 16;
  constexpr int UNITS = NT * CT;
  constexpr bool PIPE = (Cin <= 32);

  __shared__ __bf16 As[DPB * KP2];

  int t = threadIdx.x;
  int g = t / LPD, sub = t % LPD;
  int d = blockIdx.x * DPB + g;

  float acc[9][4];
  #pragma unroll
  for (int k = 0; k < 9; ++k)
    #pragma unroll
    for (int v = 0; v < 4; ++v) acc[k][v] = 0.f;
  bf16x4 xd = {};

  if (d < N) {
    int dsrc = d;
    if constexpr (REMAP) dsrc = up[d];
    xd = *reinterpret_cast<const bf16x4*>(X + (size_t)dsrc * Cin + sub * 4);
    const __bf16* Xs = X + sub * 4;
    int b0 = off[d], b1 = off[d + 1];

    if constexpr (PIPE) {
      int i = b0, rem = b1 - b0;
      uint2 ea0, ea1, ea2, ea3, eb0, eb1, eb2, eb3;
      bf16x4 xa0, xa1, xa2, xa3, xb0, xb1, xb2, xb3;
#define LOAD4(E0,E1,E2,E3,X0,X1,X2,X3,BASE) do { \
      E0 = epk[(BASE)]; E1 = epk[(BASE)+1]; E2 = epk[(BASE)+2]; E3 = epk[(BASE)+3]; \
      X0 = *reinterpret_cast<const bf16x4*>(Xs + (size_t)E0.x * Cin); \
      X1 = *reinterpret_cast<const bf16x4*>(Xs + (size_t)E1.x * Cin); \
      X2 = *reinterpret_cast<const bf16x4*>(Xs + (size_t)E2.x * Cin); \
      X3 = *reinterpret_cast<const bf16x4*>(Xs + (size_t)E3.x * Cin); } while (0)
#define EDGE4(E0,E1,E2,E3,X0,X1,X2,X3) do { \
      edge1(E0.y, X0, 1.f, acc); edge1(E1.y, X1, 1.f, acc); \
      edge1(E2.y, X2, 1.f, acc); edge1(E3.y, X3, 1.f, acc); } while (0)
      if (rem >= 8) {
        // A/B pipelined: next chunk's loads issued before current chunk's compute
        LOAD4(ea0, ea1, ea2, ea3, xa0, xa1, xa2, xa3, i);
        while (true) {
          LOAD4(eb0, eb1, eb2, eb3, xb0, xb1, xb2, xb3, i + 4);
          EDGE4(ea0, ea1, ea2, ea3, xa0, xa1, xa2, xa3);
          i += 4; rem -= 4;
          if (rem < 8) {
            EDGE4(eb0, eb1, eb2, eb3, xb0, xb1, xb2, xb3);
            i += 4; rem -= 4;
            break;
          }
          LOAD4(ea0, ea1, ea2, ea3, xa0, xa1, xa2, xa3, i + 4);
          EDGE4(eb0, eb1, eb2, eb3, xb0, xb1, xb2, xb3);
          i += 4; rem -= 4;
          if (rem < 8) {
            EDGE4(ea0, ea1, ea2, ea3, xa0, xa1, xa2, xa3);
            i += 4; rem -= 4;
            break;
          }
        }
      } else if (rem >= 4) {
        LOAD4(ea0, ea1, ea2, ea3, xa0, xa1, xa2, xa3, i);
        EDGE4(ea0, ea1, ea2, ea3, xa0, xa1, xa2, xa3);
        i += 4; rem -= 4;
      }
#undef LOAD4
#undef EDGE4
      if (rem > 0) {
        // single masked 3-wide round for the 1-3 remainder edges (clamped dup loads,
        // mask=0 contributions are exact zeros -> bit-identical result)
        int i1 = i + (rem > 1 ? 1 : 0);
        int i2 = i + (rem > 2 ? 2 : (rem > 1 ? 1 : 0));
        uint2 t0 = epk[i], t1 = epk[i1], t2 = epk[i2];
        bf16x4 y0 = *reinterpret_cast<const bf16x4*>(Xs + (size_t)t0.x * Cin);
        bf16x4 y1 = *reinterpret_cast<const bf16x4*>(Xs + (size_t)t1.x * Cin);
        bf16x4 y2 = *reinterpret_cast<const bf16x4*>(Xs + (size_t)t2.x * Cin);
        edge1(t0.y, y0, 1.f, acc);
        edge1(t1.y, y1, rem > 1 ? 1.f : 0.f, acc);
        edge1(t2.y, y2, rem > 2 ? 1.f : 0.f, acc);
      }
    } else {
      // Cin=64 path: R1-proven chunk-4 + scalar tail
      int i = b0;
      for (; i + 4 <= b1; i += 4) {
        uint2 e0 = epk[i], e1 = epk[i + 1], e2 = epk[i + 2], e3 = epk[i + 3];
        bf16x4 xf0 = *reinterpret_cast<const bf16x4*>(Xs + (size_t)e0.x * Cin);
        bf16x4 xf1 = *reinterpret_cast<const bf16x4*>(Xs + (size_t)e1.x * Cin);
        bf16x4 xf2 = *reinterpret_cast<const bf16x4*>(Xs + (size_t)e2.x * Cin);
        bf16x4 xf3 = *reinterpret_cast<const bf16x4*>(Xs + (size_t)e3.x * Cin);
        edge1(e0.y, xf0, 1.f, acc);
        edge1(e1.y, xf1, 1.f, acc);
        edge1(e2.y, xf2, 1.f, acc);
        edge1(e3.y, xf3, 1.f, acc);
      }
      for (; i < b1; ++i) {
        uint2 ep = epk[i];
        bf16x4 xf = *reinterpret_cast<const bf16x4*>(Xs + (size_t)ep.x * Cin);
        edge1(ep.y, xf, 1.f, acc);
      }
    }
  }

  __bf16* row = As + (size_t)g * KP2;
  #pragma unroll
  for (int k = 0; k < 9; ++k) {
    bf16x4 tmp;
    #pragma unroll
    for (int v = 0; v < 4; ++v) tmp[v] = (__bf16)acc[k][v];
    *reinterpret_cast<bf16x4*>(row + k * Cin + sub * 4) = tmp;
  }
  *reinterpret_cast<bf16x4*>(row + 9 * Cin + sub * 4) = xd;
  __syncthreads();

  int lane = t & 63, wave = t >> 6;
  int c15 = lane & 15, q = lane >> 4;
  for (int u = wave; u < UNITS; u += 4) {
    int tile = u / CT, ct = u - tile * CT;
    const __bf16* arow = As + (size_t)(tile * 16 + c15) * KP2 + q * 8;
    f32x4 a4 = {0.f, 0.f, 0.f, 0.f};
    #pragma unroll
    for (int kc = 0; kc < KC; ++kc) {
      bf16x8 a = *reinterpret_cast<const bf16x8*>(arow + kc * 32);
      bf16x8 b = *reinterpret_cast<const bf16x8*>(Bp + ((size_t)(kc * CT + ct) * 64 + lane) * 8);
      a4 = __builtin_amdgcn_mfma_f32_16x16x32_bf16(a, b, a4, 0, 0, 0);
    }
    int cout = ct * 16 + c15;
    float bb = bias[cout];
    #pragma unroll
    for (int r = 0; r < 4; ++r) {
      int m = q * 4 + r;
      int dd = blockIdx.x * DPB + tile * 16 + m;
      if (dd < N) {
        float vv = fmaxf(a4[r] + bb, 0.f);
        if constexpr (OUTF32)
          ((float*)outv)[(size_t)dd * outStride + cout] = vv;
        else
          ((__bf16*)outv)[(size_t)dd * outStride + cout] = (__bf16)vv;
        if constexpr (HAS_SKIP) {
          float sv = skip[(size_t)dd * Cout + cout];
          ((__bf16*)outv)[(size_t)dd * outStride + Cout + cout] = (__bf16)sv;
        }
      }
    }
  }
}

extern "C" void kernel_launch(void* const* d_in, const int* in_sizes, int n_in,
                              void* d_out, int out_size, void* d_ws, size_t ws_size,
                              hipStream_t stream) {
  const float* x0      = (const float*)d_in[0];
  const int*   up1     = (const int*)d_in[1];
  const int*   edge1v  = (const int*)d_in[2];
  const float* pseudo1 = (const float*)d_in[3];
  const float* skip1   = (const float*)d_in[4];
  const int*   up2     = (const int*)d_in[5];
  const int*   edge2v  = (const int*)d_in[6];
  const float* pseudo2 = (const float*)d_in[7];
  const float* skip2   = (const float*)d_in[8];
  const float* W1a = (const float*)d_in[9];
  const float* R1a = (const float*)d_in[10];
  const float* b1a = (const float*)d_in[11];
  const float* W2a = (const float*)d_in[12];
  const float* R2a = (const float*)d_in[13];
  const float* b2a = (const float*)d_in[14];
  const float* W1b = (const float*)d_in[15];
  const float* R1b = (const float*)d_in[16];
  const float* b1b = (const float*)d_in[17];
  const float* W2b = (const float*)d_in[18];
  const float* R2b = (const float*)d_in[19];
  const float* b2b = (const float*)d_in[20];

  const int N1 = 40000, N2 = 160000, E1 = 240000, E2 = 960000;
  const int NBK1 = 40, NBK2 = 157;
  const int NB1 = (E1 + 2047) / 2048;   // 118
  const int NB2 = (E2 + 2047) / 2048;   // 469

  char* ws = (char*)d_ws;
  __bf16* x0bf   = (__bf16*)(ws);                 // [N0,64]  1,280,000
  __bf16* xcat1  = (__bf16*)(ws +  1280000);      // [N1,64]  5,120,000
  __bf16* x3     = (__bf16*)(ws +  6400000);      // [N1,32]  2,560,000
  __bf16* h1     = (__bf16*)(ws +  8960000);      // [N1,32]  2,560,000
  __bf16* xcat2  = (__bf16*)(ws + 11520000);      // [N2,32] 10,240,000
  __bf16* x6     = (__bf16*)(ws + 21760000);      // [N2,16]  5,120,000
  int*   off1    = (int*)(ws + 26880000);         // (N1+1)*4 -> pad 160,016
  int*   off2    = (int*)(ws + 27040016);         // (N2+1)*4 -> pad 640,016
  uint2* ebuf1   = (uint2*)(ws + 27680032);       // E1*8 = 1,920,000
  uint2* epk1    = (uint2*)(ws + 29600032);       // 1,920,000
  uint2* epkR1   = (uint2*)(ws + 31520032);       // 1,920,000
  uint16_t* rbuf1 = (uint16_t*)(ws + 33440032);   // E1*2 = 480,000
  uint2* ebuf2   = (uint2*)(ws + 33920032);       // E2*8 = 7,680,000
  uint2* epk2    = (uint2*)(ws + 41600032);       // 7,680,000
  uint2* epkR2   = (uint2*)(ws + 49280032);       // 7,680,000
  uint16_t* rbuf2 = (uint16_t*)(ws + 56960032);   // E2*2 = 1,920,000
  int*   bcnt12  = (int*)(ws + 58880032);         // 512*4 (bcnt1 = +0, bcnt2 = +256)
  int*   bstart1 = (int*)(ws + 58882080);         // 256 B
  int*   bcur1   = (int*)(ws + 58882336);         // 256 B
  int*   bstart2 = (int*)(ws + 58882592);         // 1,024 B
  int*   bcur2   = (int*)(ws + 58883616);         // 1,024 B
  __bf16* BpA    = (__bf16*)(ws + 58884640);      // 40,960
  __bf16* BpB    = (__bf16*)(ws + 58925600);      // 20,480
  __bf16* BpC    = (__bf16*)(ws + 58946080);      // 10,240
  __bf16* BpD    = (__bf16*)(ws + 58956320);      //  5,120
  int* bcnt1 = bcnt12, *bcnt2 = bcnt12 + 256;

  // 1: zero both bucket-count arrays in one call
  hipMemsetAsync(bcnt12, 0, 512 * 4, stream);

  // 2: fused prologue (weight pack + x0->bf16 convert + both bucket histograms)
  k_prologue<<<150 + 625 + NB1 + NB2, 256, 0, stream>>>(
      W1a, R1a, W2a, R2a, W1b, R1b, W2b, R2b, BpA, BpB, BpC, BpD,
      (const float4*)x0, x0bf,
      edge1v + E1, E1, bcnt1, NBK1,
      edge2v + E2, E2, bcnt2, NBK2);

  // 3: dual bucket scan
  k_bscan_dual<<<2, 256, 0, stream>>>(bcnt1, NBK1, E1, bstart1, bcur1,
                                      bcnt2, NBK2, E2, bstart2, bcur2);

  // 4: dual partition (+ up[src] side stream)
  k_bpart_dual<<<NB1 + NB2, 256, 0, stream>>>(
      edge1v, edge1v + E1, (const float2*)pseudo1, up1, E1, bcur1, ebuf1, rbuf1, NBK1, NB1,
      edge2v, edge2v + E2, (const float2*)pseudo2, up2, E2, bcur2, ebuf2, rbuf2, NBK2);

  // 5: dual per-bucket CSR finalize (emits epk + remapped epkR)
  k_bcsr_dual<<<NBK1 + NBK2, 256, 0, stream>>>(
      bstart1, ebuf1, rbuf1, epk1, epkR1, off1, N1, E1, NBK1,
      bstart2, ebuf2, rbuf2, epk2, epkR2, off2, N2, E2, NBK2);

  // ---------------- level 1 convs ----------------
  // conv1 gathers x0bf (1.28MB, L2-resident) via epkR1; root via up1[d]
  k_conv<64, 32, false, true,  true ><<<N1 / 16, 256, 0, stream>>>(off1, epkR1, x0bf, BpA, b1a, skip1, up1, xcat1, N1, 64);
  k_conv<64, 32, false, false, false><<<N1 / 16, 256, 0, stream>>>(off1, epk1, xcat1, BpA, b1a, nullptr, nullptr, x3, N1, 32);
  k_conv<32, 32, false, false, false><<<N1 / 32, 256, 0, stream>>>(off1, epk1, x3, BpB, b2a, nullptr, nullptr, h1, N1, 32);

  // ---------------- level 2 convs ----------------
  // conv1 gathers h1 (2.56MB, L2-resident) via epkR2; root via up2[d]; x2 never materialized
  k_conv<32, 16, false, true,  true ><<<N2 / 32, 256, 0, stream>>>(off2, epkR2, h1, BpC, b1b, skip2, up2, xcat2, N2, 32);
  k_conv<32, 16, false, false, false><<<N2 / 32, 256, 0, stream>>>(off2, epk2, xcat2, BpC, b1b, nullptr, nullptr, x6, N2, 16);
  k_conv<16, 16, true,  false, false><<<N2 / 64, 256, 0, stream>>>(off2, epk2, x6, BpD, b2b, nullptr, nullptr, d_out, N2, 16);
}

// Round 5
// 351.603 us; speedup vs baseline: 1.5797x; 1.5797x over previous
//
#include <hip/hip_runtime.h>
#include <stdint.h>

typedef __bf16 bf16x8 __attribute__((ext_vector_type(8)));
typedef __bf16 bf16x4 __attribute__((ext_vector_type(4)));
typedef float  f32x4  __attribute__((ext_vector_type(4)));

// ================== fused prologue: packall + x0->bf16 cvt + bhist(L1) + bhist(L2) ====
__device__ __forceinline__ void d_pack(int o,
    const float* W1a, const float* R1a, const float* W2a, const float* R2a,
    const float* W1b, const float* R1b, const float* W2b, const float* R2b,
    __bf16* BpA, __bf16* BpB, __bf16* BpC, __bf16* BpD) {
  const float *W, *R; __bf16* Bp; int Cin, Cout;
  if (o < 20480)      { W = W1a; R = R1a; Bp = BpA; Cin = 64; Cout = 32; }
  else if (o < 30720) { W = W2a; R = R2a; Bp = BpB; Cin = 32; Cout = 32; o -= 20480; }
  else if (o < 35840) { W = W1b; R = R1b; Bp = BpC; Cin = 32; Cout = 16; o -= 30720; }
  else if (o < 38400) { W = W2b; R = R2b; Bp = BpD; Cin = 16; Cout = 16; o -= 35840; }
  else return;
  int CT = Cout / 16;
  int j = o & 7, lane = (o >> 3) & 63, tile = o >> 9;
  int ct = tile % CT, kc = tile / CT;
  int k = kc * 32 + ((lane >> 4) * 8) + j;
  int n = ct * 16 + (lane & 15);
  float v;
  if (k < 9 * Cin) { int k9 = k / Cin, cin = k - k9 * Cin; v = W[(k9 * Cin + cin) * Cout + n]; }
  else             { v = R[(k - 9 * Cin) * Cout + n]; }
  Bp[o] = (__bf16)v;
}

__device__ __forceinline__ void d_bhist(int b, int t, const int* dst, int E,
                                        int* bcnt, int nbk) {
  __shared__ int h[256];
  h[t] = 0;
  __syncthreads();
  int e0 = b * 2048 + t * 8;
  if (e0 + 8 <= E) {
    int4 a = *reinterpret_cast<const int4*>(dst + e0);
    int4 c = *reinterpret_cast<const int4*>(dst + e0 + 4);
    atomicAdd(&h[a.x >> 10], 1); atomicAdd(&h[a.y >> 10], 1);
    atomicAdd(&h[a.z >> 10], 1); atomicAdd(&h[a.w >> 10], 1);
    atomicAdd(&h[c.x >> 10], 1); atomicAdd(&h[c.y >> 10], 1);
    atomicAdd(&h[c.z >> 10], 1); atomicAdd(&h[c.w >> 10], 1);
  } else {
    for (int j = 0; j < 8; ++j)
      if (e0 + j < E) atomicAdd(&h[dst[e0 + j] >> 10], 1);
  }
  __syncthreads();
  if (t < nbk && h[t]) atomicAdd(&bcnt[t], h[t]);
}

__global__ __launch_bounds__(256) void k_prologue(
    const float* __restrict__ W1a, const float* __restrict__ R1a,
    const float* __restrict__ W2a, const float* __restrict__ R2a,
    const float* __restrict__ W1b, const float* __restrict__ R1b,
    const float* __restrict__ W2b, const float* __restrict__ R2b,
    __bf16* __restrict__ BpA, __bf16* __restrict__ BpB,
    __bf16* __restrict__ BpC, __bf16* __restrict__ BpD,
    const float4* __restrict__ x0, __bf16* __restrict__ x0bf,
    const int* __restrict__ dst1, int E1, int* __restrict__ bcnt1, int nbk1,
    const int* __restrict__ dst2, int E2, int* __restrict__ bcnt2, int nbk2) {
  int b = blockIdx.x, t = threadIdx.x;
  if (b < 150) {
    d_pack(b * 256 + t, W1a, R1a, W2a, R2a, W1b, R1b, W2b, R2b, BpA, BpB, BpC, BpD);
  } else if (b < 775) {
    int i = (b - 150) * 256 + t;            // N0*16 = 160,000 float4 items
    if (i < 160000) {
      float4 v = x0[i];
      bf16x4 o = {(__bf16)v.x, (__bf16)v.y, (__bf16)v.z, (__bf16)v.w};
      *reinterpret_cast<bf16x4*>(x0bf + (size_t)i * 4) = o;
    }
  } else if (b < 893) {
    d_bhist(b - 775, t, dst1, E1, bcnt1, nbk1);
  } else {
    d_bhist(b - 893, t, dst2, E2, bcnt2, nbk2);
  }
}

// ---------------- dual bucket scan: block 0 = L1, block 1 = L2 ----------------
__global__ void k_bscan_dual(const int* __restrict__ bcnt1, int nbk1, int E1,
                             int* __restrict__ bstart1, int* __restrict__ bcur1,
                             const int* __restrict__ bcnt2, int nbk2, int E2,
                             int* __restrict__ bstart2, int* __restrict__ bcur2) {
  const int* bcnt; int nbk, E; int *bstart, *bcur;
  if (blockIdx.x == 0) { bcnt = bcnt1; nbk = nbk1; E = E1; bstart = bstart1; bcur = bcur1; }
  else                 { bcnt = bcnt2; nbk = nbk2; E = E2; bstart = bstart2; bcur = bcur2; }
  __shared__ int wsum[4];
  int t = threadIdx.x, lane = t & 63, w = t >> 6;
  int v = (t < nbk) ? bcnt[t] : 0;
  int x = v;
  #pragma unroll
  for (int o = 1; o < 64; o <<= 1) { int y = __shfl_up(x, o, 64); if (lane >= o) x += y; }
  if (lane == 63) wsum[w] = x;
  __syncthreads();
  int wpre = 0;
  #pragma unroll
  for (int k = 0; k < 4; ++k) if (k < w) wpre += wsum[k];
  int excl = wpre + x - v;
  if (t < nbk) { bstart[t] = excl; bcur[t] = excl; }
  if (t == 0) bstart[nbk] = E;
}

// ---------------- dual partition: blocks [0,118) L1, [118,587) L2 ----------------
__device__ __forceinline__ void d_bpart(int b, int t, const int* src, const int* dst,
                                        const float2* pse, const int* up, int E, int* bcur,
                                        uint2* ebuf, uint16_t* rbuf, int nbk) {
  __shared__ int h[256];
  __shared__ int base[256];
  h[t] = 0;
  __syncthreads();
  int e0 = b * 2048 + t * 8;
  int d[8], rank[8];
  bool full = (e0 + 8 <= E);
  if (full) {
    int4 a = *reinterpret_cast<const int4*>(dst + e0);
    int4 c = *reinterpret_cast<const int4*>(dst + e0 + 4);
    d[0] = a.x; d[1] = a.y; d[2] = a.z; d[3] = a.w;
    d[4] = c.x; d[5] = c.y; d[6] = c.z; d[7] = c.w;
    #pragma unroll
    for (int j = 0; j < 8; ++j) rank[j] = atomicAdd(&h[d[j] >> 10], 1);
  } else {
    #pragma unroll
    for (int j = 0; j < 8; ++j)
      if (e0 + j < E) { d[j] = dst[e0 + j]; rank[j] = atomicAdd(&h[d[j] >> 10], 1); }
  }
  __syncthreads();
  if (t < nbk && h[t]) base[t] = atomicAdd(&bcur[t], h[t]);
  __syncthreads();
  if (full) {
    int4 a = *reinterpret_cast<const int4*>(src + e0);
    int4 c = *reinterpret_cast<const int4*>(src + e0 + 4);
    int s[8] = {a.x, a.y, a.z, a.w, c.x, c.y, c.z, c.w};
    int u[8];
    #pragma unroll
    for (int j = 0; j < 8; ++j) u[j] = up[s[j]];
    float2 p[8];
    #pragma unroll
    for (int j = 0; j < 8; ++j) p[j] = pse[e0 + j];
    #pragma unroll
    for (int j = 0; j < 8; ++j) {
      int bkt = d[j] >> 10, dloc = d[j] & 1023;
      union { uint uu; _Float16 hh[2]; } cv;
      cv.hh[0] = (_Float16)p[j].x; cv.hh[1] = (_Float16)p[j].y;
      int pos = base[bkt] + rank[j];
      ebuf[pos] = make_uint2((uint)s[j] | ((uint)dloc << 18), cv.uu);
      rbuf[pos] = (uint16_t)u[j];
    }
  } else {
    #pragma unroll
    for (int j = 0; j < 8; ++j) {
      if (e0 + j >= E) continue;
      int bkt = d[j] >> 10, dloc = d[j] & 1023;
      int sj = src[e0 + j];
      float2 p = pse[e0 + j];
      union { uint uu; _Float16 hh[2]; } cv;
      cv.hh[0] = (_Float16)p.x; cv.hh[1] = (_Float16)p.y;
      int pos = base[bkt] + rank[j];
      ebuf[pos] = make_uint2((uint)sj | ((uint)dloc << 18), cv.uu);
      rbuf[pos] = (uint16_t)up[sj];
    }
  }
}

__global__ __launch_bounds__(256) void k_bpart_dual(
    const int* __restrict__ src1, const int* __restrict__ dst1, const float2* __restrict__ pse1,
    const int* __restrict__ up1, int E1, int* __restrict__ bcur1,
    uint2* __restrict__ ebuf1, uint16_t* __restrict__ rbuf1, int nbk1, int NB1,
    const int* __restrict__ src2, const int* __restrict__ dst2, const float2* __restrict__ pse2,
    const int* __restrict__ up2, int E2, int* __restrict__ bcur2,
    uint2* __restrict__ ebuf2, uint16_t* __restrict__ rbuf2, int nbk2) {
  int b = blockIdx.x, t = threadIdx.x;
  if (b < NB1) d_bpart(b, t, src1, dst1, pse1, up1, E1, bcur1, ebuf1, rbuf1, nbk1);
  else         d_bpart(b - NB1, t, src2, dst2, pse2, up2, E2, bcur2, ebuf2, rbuf2, nbk2);
}

// ---------------- dual per-bucket CSR finalize: blocks [0,40) L1, [40,197) L2 ----------
__device__ __forceinline__ void d_bcsr(int b, int t, const int* bstart, const uint2* ebuf,
                                       const uint16_t* rbuf, uint2* epk, uint2* epkR,
                                       int* off, int N, int E, int nbk) {
  __shared__ int cnt[1024];
  __shared__ int excl[1024];
  __shared__ int cur[1024];
  __shared__ int wsum[4];
  int e0 = bstart[b], e1 = bstart[b + 1];
  #pragma unroll
  for (int k = 0; k < 4; ++k) { cnt[t * 4 + k] = 0; cur[t * 4 + k] = 0; }
  __syncthreads();
  for (int i = e0 + t; i < e1; i += 256)
    atomicAdd(&cnt[(ebuf[i].x >> 18) & 1023], 1);
  __syncthreads();
  int lane = t & 63, w = t >> 6;
  int i0 = t * 4;
  int c0 = cnt[i0], c1 = cnt[i0 + 1], c2 = cnt[i0 + 2], c3 = cnt[i0 + 3];
  int s = c0 + c1 + c2 + c3, x = s;
  #pragma unroll
  for (int o = 1; o < 64; o <<= 1) { int y = __shfl_up(x, o, 64); if (lane >= o) x += y; }
  if (lane == 63) wsum[w] = x;
  __syncthreads();
  int wpre = 0;
  #pragma unroll
  for (int k = 0; k < 4; ++k) if (k < w) wpre += wsum[k];
  int ex = wpre + x - s;
  excl[i0] = ex; excl[i0 + 1] = ex + c0; excl[i0 + 2] = ex + c0 + c1; excl[i0 + 3] = ex + c0 + c1 + c2;
  int dg0 = b * 1024;
  int exv[4] = {ex, ex + c0, ex + c0 + c1, ex + c0 + c1 + c2};
  #pragma unroll
  for (int k = 0; k < 4; ++k) {
    int d = dg0 + i0 + k;
    if (d < N) off[d] = e0 + exv[k];
  }
  __syncthreads();
  for (int i = e0 + t; i < e1; i += 256) {
    uint2 r = ebuf[i];
    uint rs = rbuf[i];
    int dloc = (r.x >> 18) & 1023;
    int rk = atomicAdd(&cur[dloc], 1);
    int pos = e0 + excl[dloc] + rk;
    epk[pos]  = make_uint2(r.x & 0x3FFFFu, r.y);
    epkR[pos] = make_uint2(rs, r.y);
  }
  if (b == nbk - 1 && t == 0) off[N] = E;
}

__global__ __launch_bounds__(256) void k_bcsr_dual(
    const int* __restrict__ bstart1, const uint2* __restrict__ ebuf1,
    const uint16_t* __restrict__ rbuf1, uint2* __restrict__ epk1, uint2* __restrict__ epkR1,
    int* __restrict__ off1, int N1, int E1, int nbk1,
    const int* __restrict__ bstart2, const uint2* __restrict__ ebuf2,
    const uint16_t* __restrict__ rbuf2, uint2* __restrict__ epk2, uint2* __restrict__ epkR2,
    int* __restrict__ off2, int N2, int E2, int nbk2) {
  int b = blockIdx.x, t = threadIdx.x;
  if (b < nbk1) d_bcsr(b, t, bstart1, ebuf1, rbuf1, epk1, epkR1, off1, N1, E1, nbk1);
  else          d_bcsr(b - nbk1, t, bstart2, ebuf2, rbuf2, epk2, epkR2, off2, N2, E2, nbk2);
}

// ---- per-edge spline accumulate (4 channels/thread) ----
__device__ __forceinline__ void edge1(uint ps, const bf16x4 xf, float (&acc)[9][4]) {
  union { uint u; _Float16 h[2]; } cv; cv.u = ps;
  float t0 = (float)cv.h[0], t1 = (float)cv.h[1];
  float u0 = 1.f - t0;
  float wi[3] = {0.5f * u0 * u0, -t0 * t0 + t0 + 0.5f, 0.5f * t0 * t0};
  float u1 = 1.f - t1;
  float wj[3] = {0.5f * u1 * u1, -t1 * t1 + t1 + 0.5f, 0.5f * t1 * t1};
  float xfv[4];
  #pragma unroll
  for (int v = 0; v < 4; ++v) xfv[v] = (float)xf[v];
  #pragma unroll
  for (int ki = 0; ki < 3; ++ki)
    #pragma unroll
    for (int kj = 0; kj < 3; ++kj) {
      float w = wi[ki] * wj[kj];
      #pragma unroll
      for (int v = 0; v < 4; ++v)
        acc[ki * 3 + kj][v] += w * xfv[v];
    }
}

// -------- fused spline conv: chunk-8 / chunk-4 / scalar edge loop -> LDS -> MFMA -----
// R15: revert to R1-proven structure (322us). ONLY change: a chunk-8 first stage in the
// edge loop (8 independent epk loads + 8 gathers issued back-to-back, straight-line, no
// masks, no cross-iteration state -- R12/R13/R14 failure modes excluded by construction).
// Halves serial gather rounds for the high-degree lane-groups that set the wave critical
// path (wave time = max over 8 dsts of ceil(deg/4)). State: +16 transient VGPRs; (256,4)
// cap 128 >> need. Spill tripwire: conv WRITE_SIZE >> output size.
template<int Cin, int Cout, bool OUTF32, bool HAS_SKIP, bool REMAP>
__global__ __launch_bounds__(256, 4) void k_conv(
                        const int* __restrict__ off,
                        const uint2* __restrict__ epk,
                        const __bf16* __restrict__ X, const __bf16* __restrict__ Bp,
                        const float* __restrict__ bias, const float* __restrict__ skip,
                        const int* __restrict__ up,
                        void* __restrict__ outv, int N, int outStride) {
  constexpr int LPD = Cin / 4;      // lanes per dst: 4/8/16
  constexpr int DPB = 256 / LPD;    // dsts per block: 64/32/16
  constexpr int K   = 10 * Cin;     // 160/320/640
  constexpr int KP2 = K + 8;        // LDS row stride
  constexpr int NT  = DPB / 16;     // MFMA row-tiles per block
  constexpr int KC  = K / 32;
  constexpr int CT  = Cout / 16;
  constexpr int UNITS = NT * CT;

  __shared__ __bf16 As[DPB * KP2];

  int t = threadIdx.x;
  int g = t / LPD, sub = t % LPD;
  int d = blockIdx.x * DPB + g;

  float acc[9][4];
  #pragma unroll
  for (int k = 0; k < 9; ++k)
    #pragma unroll
    for (int v = 0; v < 4; ++v) acc[k][v] = 0.f;
  bf16x4 xd = {};

  if (d < N) {
    int dsrc = d;
    if constexpr (REMAP) dsrc = up[d];
    xd = *reinterpret_cast<const bf16x4*>(X + (size_t)dsrc * Cin + sub * 4);
    const __bf16* Xs = X + sub * 4;
    int b0 = off[d], b1 = off[d + 1];
    int i = b0;
    // chunk-8: 8 gathers in flight for high-degree dsts (the wave critical path)
    for (; i + 8 <= b1; i += 8) {
      uint2 e0 = epk[i],     e1 = epk[i + 1], e2 = epk[i + 2], e3 = epk[i + 3];
      uint2 e4 = epk[i + 4], e5 = epk[i + 5], e6 = epk[i + 6], e7 = epk[i + 7];
      bf16x4 x0v = *reinterpret_cast<const bf16x4*>(Xs + (size_t)e0.x * Cin);
      bf16x4 x1v = *reinterpret_cast<const bf16x4*>(Xs + (size_t)e1.x * Cin);
      bf16x4 x2v = *reinterpret_cast<const bf16x4*>(Xs + (size_t)e2.x * Cin);
      bf16x4 x3v = *reinterpret_cast<const bf16x4*>(Xs + (size_t)e3.x * Cin);
      bf16x4 x4v = *reinterpret_cast<const bf16x4*>(Xs + (size_t)e4.x * Cin);
      bf16x4 x5v = *reinterpret_cast<const bf16x4*>(Xs + (size_t)e5.x * Cin);
      bf16x4 x6v = *reinterpret_cast<const bf16x4*>(Xs + (size_t)e6.x * Cin);
      bf16x4 x7v = *reinterpret_cast<const bf16x4*>(Xs + (size_t)e7.x * Cin);
      edge1(e0.y, x0v, acc); edge1(e1.y, x1v, acc);
      edge1(e2.y, x2v, acc); edge1(e3.y, x3v, acc);
      edge1(e4.y, x4v, acc); edge1(e5.y, x5v, acc);
      edge1(e6.y, x6v, acc); edge1(e7.y, x7v, acc);
    }
    // chunk-4 (R1-proven)
    for (; i + 4 <= b1; i += 4) {
      uint2 e0 = epk[i], e1 = epk[i + 1], e2 = epk[i + 2], e3 = epk[i + 3];
      bf16x4 x0v = *reinterpret_cast<const bf16x4*>(Xs + (size_t)e0.x * Cin);
      bf16x4 x1v = *reinterpret_cast<const bf16x4*>(Xs + (size_t)e1.x * Cin);
      bf16x4 x2v = *reinterpret_cast<const bf16x4*>(Xs + (size_t)e2.x * Cin);
      bf16x4 x3v = *reinterpret_cast<const bf16x4*>(Xs + (size_t)e3.x * Cin);
      edge1(e0.y, x0v, acc); edge1(e1.y, x1v, acc);
      edge1(e2.y, x2v, acc); edge1(e3.y, x3v, acc);
    }
    // scalar tail (R1-proven)
    for (; i < b1; ++i) {
      uint2 ep = epk[i];
      bf16x4 xf = *reinterpret_cast<const bf16x4*>(Xs + (size_t)ep.x * Cin);
      edge1(ep.y, xf, acc);
    }
  }

  __bf16* row = As + (size_t)g * KP2;
  #pragma unroll
  for (int k = 0; k < 9; ++k) {
    bf16x4 tmp;
    #pragma unroll
    for (int v = 0; v < 4; ++v) tmp[v] = (__bf16)acc[k][v];
    *reinterpret_cast<bf16x4*>(row + k * Cin + sub * 4) = tmp;
  }
  *reinterpret_cast<bf16x4*>(row + 9 * Cin + sub * 4) = xd;
  __syncthreads();

  int lane = t & 63, wave = t >> 6;
  int c15 = lane & 15, q = lane >> 4;
  for (int u = wave; u < UNITS; u += 4) {
    int tile = u / CT, ct = u - tile * CT;
    const __bf16* arow = As + (size_t)(tile * 16 + c15) * KP2 + q * 8;
    f32x4 a4 = {0.f, 0.f, 0.f, 0.f};
    #pragma unroll
    for (int kc = 0; kc < KC; ++kc) {
      bf16x8 a = *reinterpret_cast<const bf16x8*>(arow + kc * 32);
      bf16x8 b = *reinterpret_cast<const bf16x8*>(Bp + ((size_t)(kc * CT + ct) * 64 + lane) * 8);
      a4 = __builtin_amdgcn_mfma_f32_16x16x32_bf16(a, b, a4, 0, 0, 0);
    }
    int cout = ct * 16 + c15;
    float bb = bias[cout];
    #pragma unroll
    for (int r = 0; r < 4; ++r) {
      int m = q * 4 + r;
      int dd = blockIdx.x * DPB + tile * 16 + m;
      if (dd < N) {
        float vv = fmaxf(a4[r] + bb, 0.f);
        if constexpr (OUTF32)
          ((float*)outv)[(size_t)dd * outStride + cout] = vv;
        else
          ((__bf16*)outv)[(size_t)dd * outStride + cout] = (__bf16)vv;
        if constexpr (HAS_SKIP) {
          float sv = skip[(size_t)dd * Cout + cout];
          ((__bf16*)outv)[(size_t)dd * outStride + Cout + cout] = (__bf16)sv;
        }
      }
    }
  }
}

extern "C" void kernel_launch(void* const* d_in, const int* in_sizes, int n_in,
                              void* d_out, int out_size, void* d_ws, size_t ws_size,
                              hipStream_t stream) {
  const float* x0      = (const float*)d_in[0];
  const int*   up1     = (const int*)d_in[1];
  const int*   edge1v  = (const int*)d_in[2];
  const float* pseudo1 = (const float*)d_in[3];
  const float* skip1   = (const float*)d_in[4];
  const int*   up2     = (const int*)d_in[5];
  const int*   edge2v  = (const int*)d_in[6];
  const float* pseudo2 = (const float*)d_in[7];
  const float* skip2   = (const float*)d_in[8];
  const float* W1a = (const float*)d_in[9];
  const float* R1a = (const float*)d_in[10];
  const float* b1a = (const float*)d_in[11];
  const float* W2a = (const float*)d_in[12];
  const float* R2a = (const float*)d_in[13];
  const float* b2a = (const float*)d_in[14];
  const float* W1b = (const float*)d_in[15];
  const float* R1b = (const float*)d_in[16];
  const float* b1b = (const float*)d_in[17];
  const float* W2b = (const float*)d_in[18];
  const float* R2b = (const float*)d_in[19];
  const float* b2b = (const float*)d_in[20];

  const int N1 = 40000, N2 = 160000, E1 = 240000, E2 = 960000;
  const int NBK1 = 40, NBK2 = 157;
  const int NB1 = (E1 + 2047) / 2048;   // 118
  const int NB2 = (E2 + 2047) / 2048;   // 469

  char* ws = (char*)d_ws;
  __bf16* x0bf   = (__bf16*)(ws);                 // [N0,64]  1,280,000
  __bf16* xcat1  = (__bf16*)(ws +  1280000);      // [N1,64]  5,120,000
  __bf16* x3     = (__bf16*)(ws +  6400000);      // [N1,32]  2,560,000
  __bf16* h1     = (__bf16*)(ws +  8960000);      // [N1,32]  2,560,000
  __bf16* xcat2  = (__bf16*)(ws + 11520000);      // [N2,32] 10,240,000
  __bf16* x6     = (__bf16*)(ws + 21760000);      // [N2,16]  5,120,000
  int*   off1    = (int*)(ws + 26880000);         // (N1+1)*4 -> pad 160,016
  int*   off2    = (int*)(ws + 27040016);         // (N2+1)*4 -> pad 640,016
  uint2* ebuf1   = (uint2*)(ws + 27680032);       // E1*8 = 1,920,000
  uint2* epk1    = (uint2*)(ws + 29600032);       // 1,920,000
  uint2* epkR1   = (uint2*)(ws + 31520032);       // 1,920,000
  uint16_t* rbuf1 = (uint16_t*)(ws + 33440032);   // E1*2 = 480,000
  uint2* ebuf2   = (uint2*)(ws + 33920032);       // E2*8 = 7,680,000
  uint2* epk2    = (uint2*)(ws + 41600032);       // 7,680,000
  uint2* epkR2   = (uint2*)(ws + 49280032);       // 7,680,000
  uint16_t* rbuf2 = (uint16_t*)(ws + 56960032);   // E2*2 = 1,920,000
  int*   bcnt12  = (int*)(ws + 58880032);         // 512*4 (bcnt1 = +0, bcnt2 = +256)
  int*   bstart1 = (int*)(ws + 58882080);         // 256 B
  int*   bcur1   = (int*)(ws + 58882336);         // 256 B
  int*   bstart2 = (int*)(ws + 58882592);         // 1,024 B
  int*   bcur2   = (int*)(ws + 58883616);         // 1,024 B
  __bf16* BpA    = (__bf16*)(ws + 58884640);      // 40,960
  __bf16* BpB    = (__bf16*)(ws + 58925600);      // 20,480
  __bf16* BpC    = (__bf16*)(ws + 58946080);      // 10,240
  __bf16* BpD    = (__bf16*)(ws + 58956320);      //  5,120
  int* bcnt1 = bcnt12, *bcnt2 = bcnt12 + 256;

  // 1: zero both bucket-count arrays in one call
  hipMemsetAsync(bcnt12, 0, 512 * 4, stream);

  // 2: fused prologue (weight pack + x0->bf16 convert + both bucket histograms)
  k_prologue<<<150 + 625 + NB1 + NB2, 256, 0, stream>>>(
      W1a, R1a, W2a, R2a, W1b, R1b, W2b, R2b, BpA, BpB, BpC, BpD,
      (const float4*)x0, x0bf,
      edge1v + E1, E1, bcnt1, NBK1,
      edge2v + E2, E2, bcnt2, NBK2);

  // 3: dual bucket scan
  k_bscan_dual<<<2, 256, 0, stream>>>(bcnt1, NBK1, E1, bstart1, bcur1,
                                      bcnt2, NBK2, E2, bstart2, bcur2);

  // 4: dual partition (+ up[src] side stream)
  k_bpart_dual<<<NB1 + NB2, 256, 0, stream>>>(
      edge1v, edge1v + E1, (const float2*)pseudo1, up1, E1, bcur1, ebuf1, rbuf1, NBK1, NB1,
      edge2v, edge2v + E2, (const float2*)pseudo2, up2, E2, bcur2, ebuf2, rbuf2, NBK2);

  // 5: dual per-bucket CSR finalize (emits epk + remapped epkR)
  k_bcsr_dual<<<NBK1 + NBK2, 256, 0, stream>>>(
      bstart1, ebuf1, rbuf1, epk1, epkR1, off1, N1, E1, NBK1,
      bstart2, ebuf2, rbuf2, epk2, epkR2, off2, N2, E2, NBK2);

  // ---------------- level 1 convs ----------------
  // conv1 gathers x0bf (1.28MB, L2-resident) via epkR1; root via up1[d]
  k_conv<64, 32, false, true,  true ><<<N1 / 16, 256, 0, stream>>>(off1, epkR1, x0bf, BpA, b1a, skip1, up1, xcat1, N1, 64);
  k_conv<64, 32, false, false, false><<<N1 / 16, 256, 0, stream>>>(off1, epk1, xcat1, BpA, b1a, nullptr, nullptr, x3, N1, 32);
  k_conv<32, 32, false, false, false><<<N1 / 32, 256, 0, stream>>>(off1, epk1, x3, BpB, b2a, nullptr, nullptr, h1, N1, 32);

  // ---------------- level 2 convs ----------------
  // conv1 gathers h1 (2.56MB, L2-resident) via epkR2; root via up2[d]; x2 never materialized
  k_conv<32, 16, false, true,  true ><<<N2 / 32, 256, 0, stream>>>(off2, epkR2, h1, BpC, b1b, skip2, up2, xcat2, N2, 32);
  k_conv<32, 16, false, false, false><<<N2 / 32, 256, 0, stream>>>(off2, epk2, xcat2, BpC, b1b, nullptr, nullptr, x6, N2, 16);
  k_conv<16, 16, true,  false, false><<<N2 / 64, 256, 0, stream>>>(off2, epk2, x6, BpD, b2b, nullptr, nullptr, d_out, N2, 16);
}

// Round 6
// 312.210 us; speedup vs baseline: 1.7790x; 1.1262x over previous
//
#include <hip/hip_runtime.h>
#include <stdint.h>

typedef __bf16 bf16x8 __attribute__((ext_vector_type(8)));
typedef __bf16 bf16x4 __attribute__((ext_vector_type(4)));
typedef float  f32x4  __attribute__((ext_vector_type(4)));

// ================== fused prologue: packall + x0->bf16 cvt + bhist(L1) + bhist(L2) ====
__device__ __forceinline__ void d_pack(int o,
    const float* W1a, const float* R1a, const float* W2a, const float* R2a,
    const float* W1b, const float* R1b, const float* W2b, const float* R2b,
    __bf16* BpA, __bf16* BpB, __bf16* BpC, __bf16* BpD) {
  const float *W, *R; __bf16* Bp; int Cin, Cout;
  if (o < 20480)      { W = W1a; R = R1a; Bp = BpA; Cin = 64; Cout = 32; }
  else if (o < 30720) { W = W2a; R = R2a; Bp = BpB; Cin = 32; Cout = 32; o -= 20480; }
  else if (o < 35840) { W = W1b; R = R1b; Bp = BpC; Cin = 32; Cout = 16; o -= 30720; }
  else if (o < 38400) { W = W2b; R = R2b; Bp = BpD; Cin = 16; Cout = 16; o -= 35840; }
  else return;
  int CT = Cout / 16;
  int j = o & 7, lane = (o >> 3) & 63, tile = o >> 9;
  int ct = tile % CT, kc = tile / CT;
  int k = kc * 32 + ((lane >> 4) * 8) + j;
  int n = ct * 16 + (lane & 15);
  float v;
  if (k < 9 * Cin) { int k9 = k / Cin, cin = k - k9 * Cin; v = W[(k9 * Cin + cin) * Cout + n]; }
  else             { v = R[(k - 9 * Cin) * Cout + n]; }
  Bp[o] = (__bf16)v;
}

__device__ __forceinline__ void d_bhist(int b, int t, const int* dst, int E,
                                        int* bcnt, int nbk) {
  __shared__ int h[256];
  h[t] = 0;
  __syncthreads();
  int e0 = b * 2048 + t * 8;
  if (e0 + 8 <= E) {
    int4 a = *reinterpret_cast<const int4*>(dst + e0);
    int4 c = *reinterpret_cast<const int4*>(dst + e0 + 4);
    atomicAdd(&h[a.x >> 10], 1); atomicAdd(&h[a.y >> 10], 1);
    atomicAdd(&h[a.z >> 10], 1); atomicAdd(&h[a.w >> 10], 1);
    atomicAdd(&h[c.x >> 10], 1); atomicAdd(&h[c.y >> 10], 1);
    atomicAdd(&h[c.z >> 10], 1); atomicAdd(&h[c.w >> 10], 1);
  } else {
    for (int j = 0; j < 8; ++j)
      if (e0 + j < E) atomicAdd(&h[dst[e0 + j] >> 10], 1);
  }
  __syncthreads();
  if (t < nbk && h[t]) atomicAdd(&bcnt[t], h[t]);
}

__global__ __launch_bounds__(256) void k_prologue(
    const float* __restrict__ W1a, const float* __restrict__ R1a,
    const float* __restrict__ W2a, const float* __restrict__ R2a,
    const float* __restrict__ W1b, const float* __restrict__ R1b,
    const float* __restrict__ W2b, const float* __restrict__ R2b,
    __bf16* __restrict__ BpA, __bf16* __restrict__ BpB,
    __bf16* __restrict__ BpC, __bf16* __restrict__ BpD,
    const float4* __restrict__ x0, __bf16* __restrict__ x0bf,
    const int* __restrict__ dst1, int E1, int* __restrict__ bcnt1, int nbk1,
    const int* __restrict__ dst2, int E2, int* __restrict__ bcnt2, int nbk2) {
  int b = blockIdx.x, t = threadIdx.x;
  if (b < 150) {
    d_pack(b * 256 + t, W1a, R1a, W2a, R2a, W1b, R1b, W2b, R2b, BpA, BpB, BpC, BpD);
  } else if (b < 775) {
    int i = (b - 150) * 256 + t;            // N0*16 = 160,000 float4 items
    if (i < 160000) {
      float4 v = x0[i];
      bf16x4 o = {(__bf16)v.x, (__bf16)v.y, (__bf16)v.z, (__bf16)v.w};
      *reinterpret_cast<bf16x4*>(x0bf + (size_t)i * 4) = o;
    }
  } else if (b < 893) {
    d_bhist(b - 775, t, dst1, E1, bcnt1, nbk1);
  } else {
    d_bhist(b - 893, t, dst2, E2, bcnt2, nbk2);
  }
}

// ---------------- dual bucket scan: block 0 = L1, block 1 = L2 ----------------
__global__ void k_bscan_dual(const int* __restrict__ bcnt1, int nbk1, int E1,
                             int* __restrict__ bstart1, int* __restrict__ bcur1,
                             const int* __restrict__ bcnt2, int nbk2, int E2,
                             int* __restrict__ bstart2, int* __restrict__ bcur2) {
  const int* bcnt; int nbk, E; int *bstart, *bcur;
  if (blockIdx.x == 0) { bcnt = bcnt1; nbk = nbk1; E = E1; bstart = bstart1; bcur = bcur1; }
  else                 { bcnt = bcnt2; nbk = nbk2; E = E2; bstart = bstart2; bcur = bcur2; }
  __shared__ int wsum[4];
  int t = threadIdx.x, lane = t & 63, w = t >> 6;
  int v = (t < nbk) ? bcnt[t] : 0;
  int x = v;
  #pragma unroll
  for (int o = 1; o < 64; o <<= 1) { int y = __shfl_up(x, o, 64); if (lane >= o) x += y; }
  if (lane == 63) wsum[w] = x;
  __syncthreads();
  int wpre = 0;
  #pragma unroll
  for (int k = 0; k < 4; ++k) if (k < w) wpre += wsum[k];
  int excl = wpre + x - v;
  if (t < nbk) { bstart[t] = excl; bcur[t] = excl; }
  if (t == 0) bstart[nbk] = E;
}

// ---------------- dual partition: blocks [0,118) L1, [118,587) L2 ----------------
__device__ __forceinline__ void d_bpart(int b, int t, const int* src, const int* dst,
                                        const float2* pse, const int* up, int E, int* bcur,
                                        uint2* ebuf, uint16_t* rbuf, int nbk) {
  __shared__ int h[256];
  __shared__ int base[256];
  h[t] = 0;
  __syncthreads();
  int e0 = b * 2048 + t * 8;
  int d[8], rank[8];
  bool full = (e0 + 8 <= E);
  if (full) {
    int4 a = *reinterpret_cast<const int4*>(dst + e0);
    int4 c = *reinterpret_cast<const int4*>(dst + e0 + 4);
    d[0] = a.x; d[1] = a.y; d[2] = a.z; d[3] = a.w;
    d[4] = c.x; d[5] = c.y; d[6] = c.z; d[7] = c.w;
    #pragma unroll
    for (int j = 0; j < 8; ++j) rank[j] = atomicAdd(&h[d[j] >> 10], 1);
  } else {
    #pragma unroll
    for (int j = 0; j < 8; ++j)
      if (e0 + j < E) { d[j] = dst[e0 + j]; rank[j] = atomicAdd(&h[d[j] >> 10], 1); }
  }
  __syncthreads();
  if (t < nbk && h[t]) base[t] = atomicAdd(&bcur[t], h[t]);
  __syncthreads();
  if (full) {
    int4 a = *reinterpret_cast<const int4*>(src + e0);
    int4 c = *reinterpret_cast<const int4*>(src + e0 + 4);
    int s[8] = {a.x, a.y, a.z, a.w, c.x, c.y, c.z, c.w};
    int u[8];
    #pragma unroll
    for (int j = 0; j < 8; ++j) u[j] = up[s[j]];
    float2 p[8];
    #pragma unroll
    for (int j = 0; j < 8; ++j) p[j] = pse[e0 + j];
    #pragma unroll
    for (int j = 0; j < 8; ++j) {
      int bkt = d[j] >> 10, dloc = d[j] & 1023;
      union { uint uu; _Float16 hh[2]; } cv;
      cv.hh[0] = (_Float16)p[j].x; cv.hh[1] = (_Float16)p[j].y;
      int pos = base[bkt] + rank[j];
      ebuf[pos] = make_uint2((uint)s[j] | ((uint)dloc << 18), cv.uu);
      rbuf[pos] = (uint16_t)u[j];
    }
  } else {
    #pragma unroll
    for (int j = 0; j < 8; ++j) {
      if (e0 + j >= E) continue;
      int bkt = d[j] >> 10, dloc = d[j] & 1023;
      int sj = src[e0 + j];
      float2 p = pse[e0 + j];
      union { uint uu; _Float16 hh[2]; } cv;
      cv.hh[0] = (_Float16)p.x; cv.hh[1] = (_Float16)p.y;
      int pos = base[bkt] + rank[j];
      ebuf[pos] = make_uint2((uint)sj | ((uint)dloc << 18), cv.uu);
      rbuf[pos] = (uint16_t)up[sj];
    }
  }
}

__global__ __launch_bounds__(256) void k_bpart_dual(
    const int* __restrict__ src1, const int* __restrict__ dst1, const float2* __restrict__ pse1,
    const int* __restrict__ up1, int E1, int* __restrict__ bcur1,
    uint2* __restrict__ ebuf1, uint16_t* __restrict__ rbuf1, int nbk1, int NB1,
    const int* __restrict__ src2, const int* __restrict__ dst2, const float2* __restrict__ pse2,
    const int* __restrict__ up2, int E2, int* __restrict__ bcur2,
    uint2* __restrict__ ebuf2, uint16_t* __restrict__ rbuf2, int nbk2) {
  int b = blockIdx.x, t = threadIdx.x;
  if (b < NB1) d_bpart(b, t, src1, dst1, pse1, up1, E1, bcur1, ebuf1, rbuf1, nbk1);
  else         d_bpart(b - NB1, t, src2, dst2, pse2, up2, E2, bcur2, ebuf2, rbuf2, nbk2);
}

// ---------------- dual per-bucket CSR finalize (+ per-dst degree histogram) ----------
__device__ __forceinline__ void d_bcsr(int b, int t, const int* bstart, const uint2* ebuf,
                                       const uint16_t* rbuf, uint2* epk, uint2* epkR,
                                       int* off, int* dhist, int N, int E, int nbk) {
  __shared__ int cnt[1024];
  __shared__ int excl[1024];
  __shared__ int cur[1024];
  __shared__ int wsum[4];
  __shared__ int lh[64];
  int e0 = bstart[b], e1 = bstart[b + 1];
  #pragma unroll
  for (int k = 0; k < 4; ++k) { cnt[t * 4 + k] = 0; cur[t * 4 + k] = 0; }
  if (t < 64) lh[t] = 0;
  __syncthreads();
  for (int i = e0 + t; i < e1; i += 256)
    atomicAdd(&cnt[(ebuf[i].x >> 18) & 1023], 1);
  __syncthreads();
  int lane = t & 63, w = t >> 6;
  int i0 = t * 4;
  int c0 = cnt[i0], c1 = cnt[i0 + 1], c2 = cnt[i0 + 2], c3 = cnt[i0 + 3];
  int s = c0 + c1 + c2 + c3, x = s;
  #pragma unroll
  for (int o = 1; o < 64; o <<= 1) { int y = __shfl_up(x, o, 64); if (lane >= o) x += y; }
  if (lane == 63) wsum[w] = x;
  __syncthreads();
  int wpre = 0;
  #pragma unroll
  for (int k = 0; k < 4; ++k) if (k < w) wpre += wsum[k];
  int ex = wpre + x - s;
  excl[i0] = ex; excl[i0 + 1] = ex + c0; excl[i0 + 2] = ex + c0 + c1; excl[i0 + 3] = ex + c0 + c1 + c2;
  int dg0 = b * 1024;
  int exv[4] = {ex, ex + c0, ex + c0 + c1, ex + c0 + c1 + c2};
  int cv4[4] = {c0, c1, c2, c3};
  #pragma unroll
  for (int k = 0; k < 4; ++k) {
    int d = dg0 + i0 + k;
    if (d < N) {
      off[d] = e0 + exv[k];
      int c = cv4[k] > 63 ? 63 : cv4[k];
      atomicAdd(&lh[c], 1);
    }
  }
  __syncthreads();
  for (int i = e0 + t; i < e1; i += 256) {
    uint2 r = ebuf[i];
    uint rs = rbuf[i];
    int dloc = (r.x >> 18) & 1023;
    int rk = atomicAdd(&cur[dloc], 1);
    int pos = e0 + excl[dloc] + rk;
    epk[pos]  = make_uint2(r.x & 0x3FFFFu, r.y);
    epkR[pos] = make_uint2(rs, r.y);
  }
  if (t < 64 && lh[t]) atomicAdd(&dhist[t], lh[t]);
  if (b == nbk - 1 && t == 0) off[N] = E;
}

__global__ __launch_bounds__(256) void k_bcsr_dual(
    const int* __restrict__ bstart1, const uint2* __restrict__ ebuf1,
    const uint16_t* __restrict__ rbuf1, uint2* __restrict__ epk1, uint2* __restrict__ epkR1,
    int* __restrict__ off1, int* __restrict__ dh1, int N1, int E1, int nbk1,
    const int* __restrict__ bstart2, const uint2* __restrict__ ebuf2,
    const uint16_t* __restrict__ rbuf2, uint2* __restrict__ epk2, uint2* __restrict__ epkR2,
    int* __restrict__ off2, int* __restrict__ dh2, int N2, int E2, int nbk2) {
  int b = blockIdx.x, t = threadIdx.x;
  if (b < nbk1) d_bcsr(b, t, bstart1, ebuf1, rbuf1, epk1, epkR1, off1, dh1, N1, E1, nbk1);
  else          d_bcsr(b - nbk1, t, bstart2, ebuf2, rbuf2, epk2, epkR2, off2, dh2, N2, E2, nbk2);
}

// ---------------- degree-bin prep: in-place descending exclusive scan of dh[64] -------
__global__ void k_dprep(int* __restrict__ dh1, int* __restrict__ dh2) {
  int* dh = (blockIdx.x == 0) ? dh1 : dh2;
  if (threadIdx.x == 0) {
    int run = 0;
    for (int b = 63; b >= 0; --b) { int c = dh[b]; dh[b] = run; run += c; }
  }
}

// ---------------- degree-sorted dst scatter: dperm[pos] = dst (counting sort) ---------
// Within-bin order is nondeterministic but output-invariant: each dst is computed once
// and written to its own row regardless of position in dperm.
__global__ __launch_bounds__(256) void k_dscatter(
    const int* __restrict__ off1, int N1, int* __restrict__ dh1, int* __restrict__ dperm1,
    const int* __restrict__ off2, int N2, int* __restrict__ dh2, int* __restrict__ dperm2,
    int NB1s) {
  __shared__ int lh[64], lbase[64];
  int b = blockIdx.x, t = threadIdx.x;
  const int* off; int N; int* dh; int* dperm; int i;
  if (b < NB1s) { off = off1; N = N1; dh = dh1; dperm = dperm1; i = b * 256 + t; }
  else          { off = off2; N = N2; dh = dh2; dperm = dperm2; i = (b - NB1s) * 256 + t; }
  if (t < 64) lh[t] = 0;
  __syncthreads();
  int bin = 0, rank = 0;
  bool valid = (i < N);
  if (valid) {
    int deg = off[i + 1] - off[i];
    bin = deg > 63 ? 63 : deg;
    rank = atomicAdd(&lh[bin], 1);
  }
  __syncthreads();
  if (t < 64 && lh[t]) lbase[t] = atomicAdd(&dh[t], lh[t]);
  __syncthreads();
  if (valid) dperm[lbase[bin] + rank] = i;
}

// ---- per-edge spline accumulate (4 channels/thread) ----
__device__ __forceinline__ void edge1(uint ps, const bf16x4 xf, float (&acc)[9][4]) {
  union { uint u; _Float16 h[2]; } cv; cv.u = ps;
  float t0 = (float)cv.h[0], t1 = (float)cv.h[1];
  float u0 = 1.f - t0;
  float wi[3] = {0.5f * u0 * u0, -t0 * t0 + t0 + 0.5f, 0.5f * t0 * t0};
  float u1 = 1.f - t1;
  float wj[3] = {0.5f * u1 * u1, -t1 * t1 + t1 + 0.5f, 0.5f * t1 * t1};
  float xfv[4];
  #pragma unroll
  for (int v = 0; v < 4; ++v) xfv[v] = (float)xf[v];
  #pragma unroll
  for (int ki = 0; ki < 3; ++ki)
    #pragma unroll
    for (int kj = 0; kj < 3; ++kj) {
      float w = wi[ki] * wj[kj];
      #pragma unroll
      for (int v = 0; v < 4; ++v)
        acc[ki * 3 + kj][v] += w * xfv[v];
    }
}

// -------- fused spline conv, degree-sorted dst order (R16) ---------------------------
// R16: R1-proven loop structure (chunk-4 + scalar tail, (256, Cin<=32?8:4)) + dperm
// indirection. Degree sorting makes all dsts in a wave/block near-equal degree, killing
// the Poisson max-vs-mean lane waste (~45% of issued VALU was exec-masked). Bit-exact:
// same per-dst math, rows written to dperm'd locations.
template<int Cin, int Cout, bool OUTF32, bool HAS_SKIP, bool REMAP>
__global__ __launch_bounds__(256, (Cin <= 32 ? 8 : 4)) void k_conv(
                        const int* __restrict__ off,
                        const uint2* __restrict__ epk,
                        const int* __restrict__ dperm,
                        const __bf16* __restrict__ X, const __bf16* __restrict__ Bp,
                        const float* __restrict__ bias, const float* __restrict__ skip,
                        const int* __restrict__ up,
                        void* __restrict__ outv, int N, int outStride) {
  constexpr int LPD = Cin / 4;      // lanes per dst: 4/8/16
  constexpr int DPB = 256 / LPD;    // dsts per block: 64/32/16
  constexpr int K   = 10 * Cin;     // 160/320/640
  constexpr int KP2 = K + 8;        // LDS row stride
  constexpr int NT  = DPB / 16;     // MFMA row-tiles per block
  constexpr int KC  = K / 32;
  constexpr int CT  = Cout / 16;
  constexpr int UNITS = NT * CT;

  __shared__ __bf16 As[DPB * KP2];
  __shared__ int dpe[DPB];

  int t = threadIdx.x;
  int g = t / LPD, sub = t % LPD;
  if (t < DPB) dpe[t] = dperm[blockIdx.x * DPB + t];   // for the store phase (post-barrier)
  int d = dperm[blockIdx.x * DPB + g];                 // grid*DPB == N exactly (all launches)

  float acc[9][4];
  #pragma unroll
  for (int k = 0; k < 9; ++k)
    #pragma unroll
    for (int v = 0; v < 4; ++v) acc[k][v] = 0.f;
  bf16x4 xd = {};

  {
    int dsrc = d;
    if constexpr (REMAP) dsrc = up[d];
    xd = *reinterpret_cast<const bf16x4*>(X + (size_t)dsrc * Cin + sub * 4);
    const __bf16* Xs = X + sub * 4;
    int b0 = off[d], b1 = off[d + 1];
    int i = b0;
    for (; i + 4 <= b1; i += 4) {
      uint2 e0 = epk[i], e1 = epk[i + 1], e2 = epk[i + 2], e3 = epk[i + 3];
      bf16x4 x0v = *reinterpret_cast<const bf16x4*>(Xs + (size_t)e0.x * Cin);
      bf16x4 x1v = *reinterpret_cast<const bf16x4*>(Xs + (size_t)e1.x * Cin);
      bf16x4 x2v = *reinterpret_cast<const bf16x4*>(Xs + (size_t)e2.x * Cin);
      bf16x4 x3v = *reinterpret_cast<const bf16x4*>(Xs + (size_t)e3.x * Cin);
      edge1(e0.y, x0v, acc); edge1(e1.y, x1v, acc);
      edge1(e2.y, x2v, acc); edge1(e3.y, x3v, acc);
    }
    for (; i < b1; ++i) {
      uint2 ep = epk[i];
      bf16x4 xf = *reinterpret_cast<const bf16x4*>(Xs + (size_t)ep.x * Cin);
      edge1(ep.y, xf, acc);
    }
  }

  __bf16* row = As + (size_t)g * KP2;
  #pragma unroll
  for (int k = 0; k < 9; ++k) {
    bf16x4 tmp;
    #pragma unroll
    for (int v = 0; v < 4; ++v) tmp[v] = (__bf16)acc[k][v];
    *reinterpret_cast<bf16x4*>(row + k * Cin + sub * 4) = tmp;
  }
  *reinterpret_cast<bf16x4*>(row + 9 * Cin + sub * 4) = xd;
  __syncthreads();

  int lane = t & 63, wave = t >> 6;
  int c15 = lane & 15, q = lane >> 4;
  for (int u = wave; u < UNITS; u += 4) {
    int tile = u / CT, ct = u - tile * CT;
    const __bf16* arow = As + (size_t)(tile * 16 + c15) * KP2 + q * 8;
    f32x4 a4 = {0.f, 0.f, 0.f, 0.f};
    #pragma unroll
    for (int kc = 0; kc < KC; ++kc) {
      bf16x8 a = *reinterpret_cast<const bf16x8*>(arow + kc * 32);
      bf16x8 b = *reinterpret_cast<const bf16x8*>(Bp + ((size_t)(kc * CT + ct) * 64 + lane) * 8);
      a4 = __builtin_amdgcn_mfma_f32_16x16x32_bf16(a, b, a4, 0, 0, 0);
    }
    int cout = ct * 16 + c15;
    float bb = bias[cout];
    #pragma unroll
    for (int r = 0; r < 4; ++r) {
      int m = q * 4 + r;
      int dd = dpe[tile * 16 + m];
      float vv = fmaxf(a4[r] + bb, 0.f);
      if constexpr (OUTF32)
        ((float*)outv)[(size_t)dd * outStride + cout] = vv;
      else
        ((__bf16*)outv)[(size_t)dd * outStride + cout] = (__bf16)vv;
      if constexpr (HAS_SKIP) {
        float sv = skip[(size_t)dd * Cout + cout];
        ((__bf16*)outv)[(size_t)dd * outStride + Cout + cout] = (__bf16)sv;
      }
    }
  }
}

extern "C" void kernel_launch(void* const* d_in, const int* in_sizes, int n_in,
                              void* d_out, int out_size, void* d_ws, size_t ws_size,
                              hipStream_t stream) {
  const float* x0      = (const float*)d_in[0];
  const int*   up1     = (const int*)d_in[1];
  const int*   edge1v  = (const int*)d_in[2];
  const float* pseudo1 = (const float*)d_in[3];
  const float* skip1   = (const float*)d_in[4];
  const int*   up2     = (const int*)d_in[5];
  const int*   edge2v  = (const int*)d_in[6];
  const float* pseudo2 = (const float*)d_in[7];
  const float* skip2   = (const float*)d_in[8];
  const float* W1a = (const float*)d_in[9];
  const float* R1a = (const float*)d_in[10];
  const float* b1a = (const float*)d_in[11];
  const float* W2a = (const float*)d_in[12];
  const float* R2a = (const float*)d_in[13];
  const float* b2a = (const float*)d_in[14];
  const float* W1b = (const float*)d_in[15];
  const float* R1b = (const float*)d_in[16];
  const float* b1b = (const float*)d_in[17];
  const float* W2b = (const float*)d_in[18];
  const float* R2b = (const float*)d_in[19];
  const float* b2b = (const float*)d_in[20];

  const int N1 = 40000, N2 = 160000, E1 = 240000, E2 = 960000;
  const int NBK1 = 40, NBK2 = 157;
  const int NB1 = (E1 + 2047) / 2048;   // 118
  const int NB2 = (E2 + 2047) / 2048;   // 469
  const int NB1s = (N1 + 255) / 256;    // 157
  const int NB2s = (N2 + 255) / 256;    // 625

  char* ws = (char*)d_ws;
  __bf16* x0bf   = (__bf16*)(ws);                 // [N0,64]  1,280,000
  __bf16* xcat1  = (__bf16*)(ws +  1280000);      // [N1,64]  5,120,000
  __bf16* x3     = (__bf16*)(ws +  6400000);      // [N1,32]  2,560,000
  __bf16* h1     = (__bf16*)(ws +  8960000);      // [N1,32]  2,560,000
  __bf16* xcat2  = (__bf16*)(ws + 11520000);      // [N2,32] 10,240,000
  __bf16* x6     = (__bf16*)(ws + 21760000);      // [N2,16]  5,120,000
  int*   off1    = (int*)(ws + 26880000);         // (N1+1)*4 -> pad 160,016
  int*   off2    = (int*)(ws + 27040016);         // (N2+1)*4 -> pad 640,016
  uint2* ebuf1   = (uint2*)(ws + 27680032);       // E1*8 = 1,920,000
  uint2* epk1    = (uint2*)(ws + 29600032);       // 1,920,000
  uint2* epkR1   = (uint2*)(ws + 31520032);       // 1,920,000
  uint16_t* rbuf1 = (uint16_t*)(ws + 33440032);   // E1*2 = 480,000
  uint2* ebuf2   = (uint2*)(ws + 33920032);       // E2*8 = 7,680,000
  uint2* epk2    = (uint2*)(ws + 41600032);       // 7,680,000
  uint2* epkR2   = (uint2*)(ws + 49280032);       // 7,680,000
  uint16_t* rbuf2 = (uint16_t*)(ws + 56960032);   // E2*2 = 1,920,000
  int*   bcnt12  = (int*)(ws + 58880032);         // 512*4 = 2048 (bcnt1 +0, bcnt2 +256)
  int*   dh1     = (int*)(ws + 58882080);         // 64*4 = 256  (zeroed with bcnt12)
  int*   dh2     = (int*)(ws + 58882336);         // 64*4 = 256
  int*   bstart1 = (int*)(ws + 58882592);         // 256 B
  int*   bcur1   = (int*)(ws + 58882848);         // 256 B
  int*   bstart2 = (int*)(ws + 58883104);         // 1,024 B
  int*   bcur2   = (int*)(ws + 58884128);         // 1,024 B
  __bf16* BpA    = (__bf16*)(ws + 58885152);      // 40,960
  __bf16* BpB    = (__bf16*)(ws + 58926112);      // 20,480
  __bf16* BpC    = (__bf16*)(ws + 58946592);      // 10,240
  __bf16* BpD    = (__bf16*)(ws + 58956832);      //  5,120
  int*   dperm1  = (int*)(ws + 58961952);         // N1*4 = 160,000
  int*   dperm2  = (int*)(ws + 59121952);         // N2*4 = 640,000  -> end 59,761,952
  int* bcnt1 = bcnt12, *bcnt2 = bcnt12 + 256;

  // 1: zero bucket counts + both degree histograms (contiguous) in one call
  hipMemsetAsync(bcnt12, 0, 2048 + 512, stream);

  // 2: fused prologue (weight pack + x0->bf16 convert + both bucket histograms)
  k_prologue<<<150 + 625 + NB1 + NB2, 256, 0, stream>>>(
      W1a, R1a, W2a, R2a, W1b, R1b, W2b, R2b, BpA, BpB, BpC, BpD,
      (const float4*)x0, x0bf,
      edge1v + E1, E1, bcnt1, NBK1,
      edge2v + E2, E2, bcnt2, NBK2);

  // 3: dual bucket scan
  k_bscan_dual<<<2, 256, 0, stream>>>(bcnt1, NBK1, E1, bstart1, bcur1,
                                      bcnt2, NBK2, E2, bstart2, bcur2);

  // 4: dual partition (+ up[src] side stream)
  k_bpart_dual<<<NB1 + NB2, 256, 0, stream>>>(
      edge1v, edge1v + E1, (const float2*)pseudo1, up1, E1, bcur1, ebuf1, rbuf1, NBK1, NB1,
      edge2v, edge2v + E2, (const float2*)pseudo2, up2, E2, bcur2, ebuf2, rbuf2, NBK2);

  // 5: dual per-bucket CSR finalize (epk + epkR + per-dst degree histogram)
  k_bcsr_dual<<<NBK1 + NBK2, 256, 0, stream>>>(
      bstart1, ebuf1, rbuf1, epk1, epkR1, off1, dh1, N1, E1, NBK1,
      bstart2, ebuf2, rbuf2, epk2, epkR2, off2, dh2, N2, E2, NBK2);

  // 6: degree-bin prefix (descending) in place
  k_dprep<<<2, 64, 0, stream>>>(dh1, dh2);

  // 7: counting-sort scatter -> dperm (degree-sorted dst order)
  k_dscatter<<<NB1s + NB2s, 256, 0, stream>>>(off1, N1, dh1, dperm1,
                                              off2, N2, dh2, dperm2, NB1s);

  // ---------------- level 1 convs ----------------
  // conv1 gathers x0bf (1.28MB, L2-resident) via epkR1; root via up1[d]
  k_conv<64, 32, false, true,  true ><<<N1 / 16, 256, 0, stream>>>(off1, epkR1, dperm1, x0bf, BpA, b1a, skip1, up1, xcat1, N1, 64);
  k_conv<64, 32, false, false, false><<<N1 / 16, 256, 0, stream>>>(off1, epk1, dperm1, xcat1, BpA, b1a, nullptr, nullptr, x3, N1, 32);
  k_conv<32, 32, false, false, false><<<N1 / 32, 256, 0, stream>>>(off1, epk1, dperm1, x3, BpB, b2a, nullptr, nullptr, h1, N1, 32);

  // ---------------- level 2 convs ----------------
  // conv1 gathers h1 (2.56MB, L2-resident) via epkR2; root via up2[d]; x2 never materialized
  k_conv<32, 16, false, true,  true ><<<N2 / 32, 256, 0, stream>>>(off2, epkR2, dperm2, h1, BpC, b1b, skip2, up2, xcat2, N2, 32);
  k_conv<32, 16, false, false, false><<<N2 / 32, 256, 0, stream>>>(off2, epk2, dperm2, xcat2, BpC, b1b, nullptr, nullptr, x6, N2, 16);
  k_conv<16, 16, true,  false, false><<<N2 / 64, 256, 0, stream>>>(off2, epk2, dperm2, x6, BpD, b2b, nullptr, nullptr, d_out, N2, 16);
}

// Round 8
// 301.633 us; speedup vs baseline: 1.8414x; 1.0351x over previous
//
#include <hip/hip_runtime.h>
#include <stdint.h>

typedef __bf16 bf16x8 __attribute__((ext_vector_type(8)));
typedef __bf16 bf16x4 __attribute__((ext_vector_type(4)));
typedef float  f32x4  __attribute__((ext_vector_type(4)));
typedef float  f32x2  __attribute__((ext_vector_type(2)));

// ================== fused prologue: packall + x0->bf16 cvt + bhist(L1) + bhist(L2) ====
__device__ __forceinline__ void d_pack(int o,
    const float* W1a, const float* R1a, const float* W2a, const float* R2a,
    const float* W1b, const float* R1b, const float* W2b, const float* R2b,
    __bf16* BpA, __bf16* BpB, __bf16* BpC, __bf16* BpD) {
  const float *W, *R; __bf16* Bp; int Cin, Cout;
  if (o < 20480)      { W = W1a; R = R1a; Bp = BpA; Cin = 64; Cout = 32; }
  else if (o < 30720) { W = W2a; R = R2a; Bp = BpB; Cin = 32; Cout = 32; o -= 20480; }
  else if (o < 35840) { W = W1b; R = R1b; Bp = BpC; Cin = 32; Cout = 16; o -= 30720; }
  else if (o < 38400) { W = W2b; R = R2b; Bp = BpD; Cin = 16; Cout = 16; o -= 35840; }
  else return;
  int CT = Cout / 16;
  int j = o & 7, lane = (o >> 3) & 63, tile = o >> 9;
  int ct = tile % CT, kc = tile / CT;
  int k = kc * 32 + ((lane >> 4) * 8) + j;
  int n = ct * 16 + (lane & 15);
  float v;
  if (k < 9 * Cin) { int k9 = k / Cin, cin = k - k9 * Cin; v = W[(k9 * Cin + cin) * Cout + n]; }
  else             { v = R[(k - 9 * Cin) * Cout + n]; }
  Bp[o] = (__bf16)v;
}

__device__ __forceinline__ void d_bhist(int b, int t, const int* dst, int E,
                                        int* bcnt, int nbk) {
  __shared__ int h[256];
  h[t] = 0;
  __syncthreads();
  int e0 = b * 2048 + t * 8;
  if (e0 + 8 <= E) {
    int4 a = *reinterpret_cast<const int4*>(dst + e0);
    int4 c = *reinterpret_cast<const int4*>(dst + e0 + 4);
    atomicAdd(&h[a.x >> 10], 1); atomicAdd(&h[a.y >> 10], 1);
    atomicAdd(&h[a.z >> 10], 1); atomicAdd(&h[a.w >> 10], 1);
    atomicAdd(&h[c.x >> 10], 1); atomicAdd(&h[c.y >> 10], 1);
    atomicAdd(&h[c.z >> 10], 1); atomicAdd(&h[c.w >> 10], 1);
  } else {
    for (int j = 0; j < 8; ++j)
      if (e0 + j < E) atomicAdd(&h[dst[e0 + j] >> 10], 1);
  }
  __syncthreads();
  if (t < nbk && h[t]) atomicAdd(&bcnt[t], h[t]);
}

__global__ __launch_bounds__(256) void k_prologue(
    const float* __restrict__ W1a, const float* __restrict__ R1a,
    const float* __restrict__ W2a, const float* __restrict__ R2a,
    const float* __restrict__ W1b, const float* __restrict__ R1b,
    const float* __restrict__ W2b, const float* __restrict__ R2b,
    __bf16* __restrict__ BpA, __bf16* __restrict__ BpB,
    __bf16* __restrict__ BpC, __bf16* __restrict__ BpD,
    const float4* __restrict__ x0, __bf16* __restrict__ x0bf,
    const int* __restrict__ dst1, int E1, int* __restrict__ bcnt1, int nbk1,
    const int* __restrict__ dst2, int E2, int* __restrict__ bcnt2, int nbk2) {
  int b = blockIdx.x, t = threadIdx.x;
  if (b < 150) {
    d_pack(b * 256 + t, W1a, R1a, W2a, R2a, W1b, R1b, W2b, R2b, BpA, BpB, BpC, BpD);
  } else if (b < 775) {
    int i = (b - 150) * 256 + t;            // N0*16 = 160,000 float4 items
    if (i < 160000) {
      float4 v = x0[i];
      bf16x4 o = {(__bf16)v.x, (__bf16)v.y, (__bf16)v.z, (__bf16)v.w};
      *reinterpret_cast<bf16x4*>(x0bf + (size_t)i * 4) = o;
    }
  } else if (b < 893) {
    d_bhist(b - 775, t, dst1, E1, bcnt1, nbk1);
  } else {
    d_bhist(b - 893, t, dst2, E2, bcnt2, nbk2);
  }
}

// ---------------- dual bucket scan: block 0 = L1, block 1 = L2 ----------------
__global__ void k_bscan_dual(const int* __restrict__ bcnt1, int nbk1, int E1,
                             int* __restrict__ bstart1, int* __restrict__ bcur1,
                             const int* __restrict__ bcnt2, int nbk2, int E2,
                             int* __restrict__ bstart2, int* __restrict__ bcur2) {
  const int* bcnt; int nbk, E; int *bstart, *bcur;
  if (blockIdx.x == 0) { bcnt = bcnt1; nbk = nbk1; E = E1; bstart = bstart1; bcur = bcur1; }
  else                 { bcnt = bcnt2; nbk = nbk2; E = E2; bstart = bstart2; bcur = bcur2; }
  __shared__ int wsum[4];
  int t = threadIdx.x, lane = t & 63, w = t >> 6;
  int v = (t < nbk) ? bcnt[t] : 0;
  int x = v;
  #pragma unroll
  for (int o = 1; o < 64; o <<= 1) { int y = __shfl_up(x, o, 64); if (lane >= o) x += y; }
  if (lane == 63) wsum[w] = x;
  __syncthreads();
  int wpre = 0;
  #pragma unroll
  for (int k = 0; k < 4; ++k) if (k < w) wpre += wsum[k];
  int excl = wpre + x - v;
  if (t < nbk) { bstart[t] = excl; bcur[t] = excl; }
  if (t == 0) bstart[nbk] = E;
}

// ---------------- dual partition: blocks [0,118) L1, [118,587) L2 ----------------
__device__ __forceinline__ void d_bpart(int b, int t, const int* src, const int* dst,
                                        const float2* pse, const int* up, int E, int* bcur,
                                        uint2* ebuf, uint16_t* rbuf, int nbk) {
  __shared__ int h[256];
  __shared__ int base[256];
  h[t] = 0;
  __syncthreads();
  int e0 = b * 2048 + t * 8;
  int d[8], rank[8];
  bool full = (e0 + 8 <= E);
  if (full) {
    int4 a = *reinterpret_cast<const int4*>(dst + e0);
    int4 c = *reinterpret_cast<const int4*>(dst + e0 + 4);
    d[0] = a.x; d[1] = a.y; d[2] = a.z; d[3] = a.w;
    d[4] = c.x; d[5] = c.y; d[6] = c.z; d[7] = c.w;
    #pragma unroll
    for (int j = 0; j < 8; ++j) rank[j] = atomicAdd(&h[d[j] >> 10], 1);
  } else {
    #pragma unroll
    for (int j = 0; j < 8; ++j)
      if (e0 + j < E) { d[j] = dst[e0 + j]; rank[j] = atomicAdd(&h[d[j] >> 10], 1); }
  }
  __syncthreads();
  if (t < nbk && h[t]) base[t] = atomicAdd(&bcur[t], h[t]);
  __syncthreads();
  if (full) {
    int4 a = *reinterpret_cast<const int4*>(src + e0);
    int4 c = *reinterpret_cast<const int4*>(src + e0 + 4);
    int s[8] = {a.x, a.y, a.z, a.w, c.x, c.y, c.z, c.w};
    int u[8];
    #pragma unroll
    for (int j = 0; j < 8; ++j) u[j] = up[s[j]];
    float2 p[8];
    #pragma unroll
    for (int j = 0; j < 8; ++j) p[j] = pse[e0 + j];
    #pragma unroll
    for (int j = 0; j < 8; ++j) {
      int bkt = d[j] >> 10, dloc = d[j] & 1023;
      union { uint uu; _Float16 hh[2]; } cv;
      cv.hh[0] = (_Float16)p[j].x; cv.hh[1] = (_Float16)p[j].y;
      int pos = base[bkt] + rank[j];
      ebuf[pos] = make_uint2((uint)s[j] | ((uint)dloc << 18), cv.uu);
      rbuf[pos] = (uint16_t)u[j];
    }
  } else {
    #pragma unroll
    for (int j = 0; j < 8; ++j) {
      if (e0 + j >= E) continue;
      int bkt = d[j] >> 10, dloc = d[j] & 1023;
      int sj = src[e0 + j];
      float2 p = pse[e0 + j];
      union { uint uu; _Float16 hh[2]; } cv;
      cv.hh[0] = (_Float16)p.x; cv.hh[1] = (_Float16)p.y;
      int pos = base[bkt] + rank[j];
      ebuf[pos] = make_uint2((uint)sj | ((uint)dloc << 18), cv.uu);
      rbuf[pos] = (uint16_t)up[sj];
    }
  }
}

__global__ __launch_bounds__(256) void k_bpart_dual(
    const int* __restrict__ src1, const int* __restrict__ dst1, const float2* __restrict__ pse1,
    const int* __restrict__ up1, int E1, int* __restrict__ bcur1,
    uint2* __restrict__ ebuf1, uint16_t* __restrict__ rbuf1, int nbk1, int NB1,
    const int* __restrict__ src2, const int* __restrict__ dst2, const float2* __restrict__ pse2,
    const int* __restrict__ up2, int E2, int* __restrict__ bcur2,
    uint2* __restrict__ ebuf2, uint16_t* __restrict__ rbuf2, int nbk2) {
  int b = blockIdx.x, t = threadIdx.x;
  if (b < NB1) d_bpart(b, t, src1, dst1, pse1, up1, E1, bcur1, ebuf1, rbuf1, nbk1);
  else         d_bpart(b - NB1, t, src2, dst2, pse2, up2, E2, bcur2, ebuf2, rbuf2, nbk2);
}

// ---------------- dual per-bucket CSR finalize (+ per-dst degree histogram) ----------
__device__ __forceinline__ void d_bcsr(int b, int t, const int* bstart, const uint2* ebuf,
                                       const uint16_t* rbuf, uint2* epk, uint2* epkR,
                                       int* off, int* dhist, int N, int E, int nbk) {
  __shared__ int cnt[1024];
  __shared__ int excl[1024];
  __shared__ int cur[1024];
  __shared__ int wsum[4];
  __shared__ int lh[64];
  int e0 = bstart[b], e1 = bstart[b + 1];
  #pragma unroll
  for (int k = 0; k < 4; ++k) { cnt[t * 4 + k] = 0; cur[t * 4 + k] = 0; }
  if (t < 64) lh[t] = 0;
  __syncthreads();
  for (int i = e0 + t; i < e1; i += 256)
    atomicAdd(&cnt[(ebuf[i].x >> 18) & 1023], 1);
  __syncthreads();
  int lane = t & 63, w = t >> 6;
  int i0 = t * 4;
  int c0 = cnt[i0], c1 = cnt[i0 + 1], c2 = cnt[i0 + 2], c3 = cnt[i0 + 3];
  int s = c0 + c1 + c2 + c3, x = s;
  #pragma unroll
  for (int o = 1; o < 64; o <<= 1) { int y = __shfl_up(x, o, 64); if (lane >= o) x += y; }
  if (lane == 63) wsum[w] = x;
  __syncthreads();
  int wpre = 0;
  #pragma unroll
  for (int k = 0; k < 4; ++k) if (k < w) wpre += wsum[k];
  int ex = wpre + x - s;
  excl[i0] = ex; excl[i0 + 1] = ex + c0; excl[i0 + 2] = ex + c0 + c1; excl[i0 + 3] = ex + c0 + c1 + c2;
  int dg0 = b * 1024;
  int exv[4] = {ex, ex + c0, ex + c0 + c1, ex + c0 + c1 + c2};
  int cv4[4] = {c0, c1, c2, c3};
  #pragma unroll
  for (int k = 0; k < 4; ++k) {
    int d = dg0 + i0 + k;
    if (d < N) {
      off[d] = e0 + exv[k];
      int c = cv4[k] > 63 ? 63 : cv4[k];
      atomicAdd(&lh[c], 1);
    }
  }
  __syncthreads();
  for (int i = e0 + t; i < e1; i += 256) {
    uint2 r = ebuf[i];
    uint rs = rbuf[i];
    int dloc = (r.x >> 18) & 1023;
    int rk = atomicAdd(&cur[dloc], 1);
    int pos = e0 + excl[dloc] + rk;
    epk[pos]  = make_uint2(r.x & 0x3FFFFu, r.y);
    epkR[pos] = make_uint2(rs, r.y);
  }
  if (t < 64 && lh[t]) atomicAdd(&dhist[t], lh[t]);
  if (b == nbk - 1 && t == 0) off[N] = E;
}

__global__ __launch_bounds__(256) void k_bcsr_dual(
    const int* __restrict__ bstart1, const uint2* __restrict__ ebuf1,
    const uint16_t* __restrict__ rbuf1, uint2* __restrict__ epk1, uint2* __restrict__ epkR1,
    int* __restrict__ off1, int* __restrict__ dh1, int N1, int E1, int nbk1,
    const int* __restrict__ bstart2, const uint2* __restrict__ ebuf2,
    const uint16_t* __restrict__ rbuf2, uint2* __restrict__ epk2, uint2* __restrict__ epkR2,
    int* __restrict__ off2, int* __restrict__ dh2, int N2, int E2, int nbk2) {
  int b = blockIdx.x, t = threadIdx.x;
  if (b < nbk1) d_bcsr(b, t, bstart1, ebuf1, rbuf1, epk1, epkR1, off1, dh1, N1, E1, nbk1);
  else          d_bcsr(b - nbk1, t, bstart2, ebuf2, rbuf2, epk2, epkR2, off2, dh2, N2, E2, nbk2);
}

// ---------------- degree-bin prep: in-place descending exclusive scan of dh[64] -------
__global__ void k_dprep(int* __restrict__ dh1, int* __restrict__ dh2) {
  int* dh = (blockIdx.x == 0) ? dh1 : dh2;
  if (threadIdx.x == 0) {
    int run = 0;
    for (int b = 63; b >= 0; --b) { int c = dh[b]; dh[b] = run; run += c; }
  }
}

// ---------------- degree-sorted dst scatter: dperm[pos] = dst (counting sort) ---------
__global__ __launch_bounds__(256) void k_dscatter(
    const int* __restrict__ off1, int N1, int* __restrict__ dh1, int* __restrict__ dperm1,
    const int* __restrict__ off2, int N2, int* __restrict__ dh2, int* __restrict__ dperm2,
    int NB1s) {
  __shared__ int lh[64], lbase[64];
  int b = blockIdx.x, t = threadIdx.x;
  const int* off; int N; int* dh; int* dperm; int i;
  if (b < NB1s) { off = off1; N = N1; dh = dh1; dperm = dperm1; i = b * 256 + t; }
  else          { off = off2; N = N2; dh = dh2; dperm = dperm2; i = (b - NB1s) * 256 + t; }
  if (t < 64) lh[t] = 0;
  __syncthreads();
  int bin = 0, rank = 0;
  bool valid = (i < N);
  if (valid) {
    int deg = off[i + 1] - off[i];
    bin = deg > 63 ? 63 : deg;
    rank = atomicAdd(&lh[bin], 1);
  }
  __syncthreads();
  if (t < 64 && lh[t]) lbase[t] = atomicAdd(&dh[t], lh[t]);
  __syncthreads();
  if (valid) dperm[lbase[bin] + rank] = i;
}

// ---- per-edge spline accumulate, packed-f32 (R17): acc as f32x2 pairs so the 36
// scalar FMAs become 18 v_pk_fma_f32 (VOP3P). Same math per channel -> bit-identical.
__device__ __forceinline__ void edge1(uint ps, const bf16x4 xf, f32x2 (&acc)[9][2]) {
  union { uint u; _Float16 h[2]; } cv; cv.u = ps;
  float t0 = (float)cv.h[0], t1 = (float)cv.h[1];
  float u0 = 1.f - t0;
  float wi0 = 0.5f * u0 * u0, wi1 = -t0 * t0 + t0 + 0.5f, wi2 = 0.5f * t0 * t0;
  float u1 = 1.f - t1;
  float wj0 = 0.5f * u1 * u1, wj1 = -t1 * t1 + t1 + 0.5f, wj2 = 0.5f * t1 * t1;
  float w[9] = {wi0 * wj0, wi0 * wj1, wi0 * wj2,
                wi1 * wj0, wi1 * wj1, wi1 * wj2,
                wi2 * wj0, wi2 * wj1, wi2 * wj2};
  f32x2 xlo = {(float)xf[0], (float)xf[1]};
  f32x2 xhi = {(float)xf[2], (float)xf[3]};
  #pragma unroll
  for (int k = 0; k < 9; ++k) {
    f32x2 wv = {w[k], w[k]};
    acc[k][0] += wv * xlo;
    acc[k][1] += wv * xhi;
  }
}

// -------- fused spline conv, degree-sorted dst order + packed-f32 edge math ----------
// R17 = R16 structure verbatim (chunk-4 + scalar tail, dperm, (256, Cin<=32?8:4)).
// Only edge1/acc changed to f32x2 packed pairs (all indices compile-time -> registers).
template<int Cin, int Cout, bool OUTF32, bool HAS_SKIP, bool REMAP>
__global__ __launch_bounds__(256, (Cin <= 32 ? 8 : 4)) void k_conv(
                        const int* __restrict__ off,
                        const uint2* __restrict__ epk,
                        const int* __restrict__ dperm,
                        const __bf16* __restrict__ X, const __bf16* __restrict__ Bp,
                        const float* __restrict__ bias, const float* __restrict__ skip,
                        const int* __restrict__ up,
                        void* __restrict__ outv, int N, int outStride) {
  constexpr int LPD = Cin / 4;      // lanes per dst: 4/8/16
  constexpr int DPB = 256 / LPD;    // dsts per block: 64/32/16
  constexpr int K   = 10 * Cin;     // 160/320/640
  constexpr int KP2 = K + 8;        // LDS row stride
  constexpr int NT  = DPB / 16;     // MFMA row-tiles per block
  constexpr int KC  = K / 32;
  constexpr int CT  = Cout / 16;
  constexpr int UNITS = NT * CT;

  __shared__ __bf16 As[DPB * KP2];
  __shared__ int dpe[DPB];

  int t = threadIdx.x;
  int g = t / LPD, sub = t % LPD;
  if (t < DPB) dpe[t] = dperm[blockIdx.x * DPB + t];   // for the store phase (post-barrier)
  int d = dperm[blockIdx.x * DPB + g];                 // grid*DPB == N exactly (all launches)

  f32x2 acc[9][2];
  #pragma unroll
  for (int k = 0; k < 9; ++k) {
    acc[k][0] = (f32x2){0.f, 0.f};
    acc[k][1] = (f32x2){0.f, 0.f};
  }
  bf16x4 xd = {};

  {
    int dsrc = d;
    if constexpr (REMAP) dsrc = up[d];
    xd = *reinterpret_cast<const bf16x4*>(X + (size_t)dsrc * Cin + sub * 4);
    const __bf16* Xs = X + sub * 4;
    int b0 = off[d], b1 = off[d + 1];
    int i = b0;
    for (; i + 4 <= b1; i += 4) {
      uint2 e0 = epk[i], e1 = epk[i + 1], e2 = epk[i + 2], e3 = epk[i + 3];
      bf16x4 x0v = *reinterpret_cast<const bf16x4*>(Xs + (size_t)e0.x * Cin);
      bf16x4 x1v = *reinterpret_cast<const bf16x4*>(Xs + (size_t)e1.x * Cin);
      bf16x4 x2v = *reinterpret_cast<const bf16x4*>(Xs + (size_t)e2.x * Cin);
      bf16x4 x3v = *reinterpret_cast<const bf16x4*>(Xs + (size_t)e3.x * Cin);
      edge1(e0.y, x0v, acc); edge1(e1.y, x1v, acc);
      edge1(e2.y, x2v, acc); edge1(e3.y, x3v, acc);
    }
    for (; i < b1; ++i) {
      uint2 ep = epk[i];
      bf16x4 xf = *reinterpret_cast<const bf16x4*>(Xs + (size_t)ep.x * Cin);
      edge1(ep.y, xf, acc);
    }
  }

  __bf16* row = As + (size_t)g * KP2;
  #pragma unroll
  for (int k = 0; k < 9; ++k) {
    bf16x4 tmp;
    tmp[0] = (__bf16)acc[k][0][0];
    tmp[1] = (__bf16)acc[k][0][1];
    tmp[2] = (__bf16)acc[k][1][0];
    tmp[3] = (__bf16)acc[k][1][1];
    *reinterpret_cast<bf16x4*>(row + k * Cin + sub * 4) = tmp;
  }
  *reinterpret_cast<bf16x4*>(row + 9 * Cin + sub * 4) = xd;
  __syncthreads();

  int lane = t & 63, wave = t >> 6;
  int c15 = lane & 15, q = lane >> 4;
  for (int u = wave; u < UNITS; u += 4) {
    int tile = u / CT, ct = u - tile * CT;
    const __bf16* arow = As + (size_t)(tile * 16 + c15) * KP2 + q * 8;
    f32x4 a4 = {0.f, 0.f, 0.f, 0.f};
    #pragma unroll
    for (int kc = 0; kc < KC; ++kc) {
      bf16x8 a = *reinterpret_cast<const bf16x8*>(arow + kc * 32);
      bf16x8 b = *reinterpret_cast<const bf16x8*>(Bp + ((size_t)(kc * CT + ct) * 64 + lane) * 8);
      a4 = __builtin_amdgcn_mfma_f32_16x16x32_bf16(a, b, a4, 0, 0, 0);
    }
    int cout = ct * 16 + c15;
    float bb = bias[cout];
    #pragma unroll
    for (int r = 0; r < 4; ++r) {
      int m = q * 4 + r;
      int dd = dpe[tile * 16 + m];
      float vv = fmaxf(a4[r] + bb, 0.f);
      if constexpr (OUTF32)
        ((float*)outv)[(size_t)dd * outStride + cout] = vv;
      else
        ((__bf16*)outv)[(size_t)dd * outStride + cout] = (__bf16)vv;
      if constexpr (HAS_SKIP) {
        float sv = skip[(size_t)dd * Cout + cout];
        ((__bf16*)outv)[(size_t)dd * outStride + Cout + cout] = (__bf16)sv;
      }
    }
  }
}

extern "C" void kernel_launch(void* const* d_in, const int* in_sizes, int n_in,
                              void* d_out, int out_size, void* d_ws, size_t ws_size,
                              hipStream_t stream) {
  const float* x0      = (const float*)d_in[0];
  const int*   up1     = (const int*)d_in[1];
  const int*   edge1v  = (const int*)d_in[2];
  const float* pseudo1 = (const float*)d_in[3];
  const float* skip1   = (const float*)d_in[4];
  const int*   up2     = (const int*)d_in[5];
  const int*   edge2v  = (const int*)d_in[6];
  const float* pseudo2 = (const float*)d_in[7];
  const float* skip2   = (const float*)d_in[8];
  const float* W1a = (const float*)d_in[9];
  const float* R1a = (const float*)d_in[10];
  const float* b1a = (const float*)d_in[11];
  const float* W2a = (const float*)d_in[12];
  const float* R2a = (const float*)d_in[13];
  const float* b2a = (const float*)d_in[14];
  const float* W1b = (const float*)d_in[15];
  const float* R1b = (const float*)d_in[16];
  const float* b1b = (const float*)d_in[17];
  const float* W2b = (const float*)d_in[18];
  const float* R2b = (const float*)d_in[19];
  const float* b2b = (const float*)d_in[20];

  const int N1 = 40000, N2 = 160000, E1 = 240000, E2 = 960000;
  const int NBK1 = 40, NBK2 = 157;
  const int NB1 = (E1 + 2047) / 2048;   // 118
  const int NB2 = (E2 + 2047) / 2048;   // 469
  const int NB1s = (N1 + 255) / 256;    // 157
  const int NB2s = (N2 + 255) / 256;    // 625

  char* ws = (char*)d_ws;
  __bf16* x0bf   = (__bf16*)(ws);                 // [N0,64]  1,280,000
  __bf16* xcat1  = (__bf16*)(ws +  1280000);      // [N1,64]  5,120,000
  __bf16* x3     = (__bf16*)(ws +  6400000);      // [N1,32]  2,560,000
  __bf16* h1     = (__bf16*)(ws +  8960000);      // [N1,32]  2,560,000
  __bf16* xcat2  = (__bf16*)(ws + 11520000);      // [N2,32] 10,240,000
  __bf16* x6     = (__bf16*)(ws + 21760000);      // [N2,16]  5,120,000
  int*   off1    = (int*)(ws + 26880000);         // (N1+1)*4 -> pad 160,016
  int*   off2    = (int*)(ws + 27040016);         // (N2+1)*4 -> pad 640,016
  uint2* ebuf1   = (uint2*)(ws + 27680032);       // E1*8 = 1,920,000
  uint2* epk1    = (uint2*)(ws + 29600032);       // 1,920,000
  uint2* epkR1   = (uint2*)(ws + 31520032);       // 1,920,000
  uint16_t* rbuf1 = (uint16_t*)(ws + 33440032);   // E1*2 = 480,000
  uint2* ebuf2   = (uint2*)(ws + 33920032);       // E2*8 = 7,680,000
  uint2* epk2    = (uint2*)(ws + 41600032);       // 7,680,000
  uint2* epkR2   = (uint2*)(ws + 49280032);       // 7,680,000
  uint16_t* rbuf2 = (uint16_t*)(ws + 56960032);   // E2*2 = 1,920,000
  int*   bcnt12  = (int*)(ws + 58880032);         // 512*4 = 2048 (bcnt1 +0, bcnt2 +256)
  int*   dh1     = (int*)(ws + 58882080);         // 64*4 = 256  (zeroed with bcnt12)
  int*   dh2     = (int*)(ws + 58882336);         // 64*4 = 256
  int*   bstart1 = (int*)(ws + 58882592);         // 256 B
  int*   bcur1   = (int*)(ws + 58882848);         // 256 B
  int*   bstart2 = (int*)(ws + 58883104);         // 1,024 B
  int*   bcur2   = (int*)(ws + 58884128);         // 1,024 B
  __bf16* BpA    = (__bf16*)(ws + 58885152);      // 40,960
  __bf16* BpB    = (__bf16*)(ws + 58926112);      // 20,480
  __bf16* BpC    = (__bf16*)(ws + 58946592);      // 10,240
  __bf16* BpD    = (__bf16*)(ws + 58956832);      //  5,120
  int*   dperm1  = (int*)(ws + 58961952);         // N1*4 = 160,000
  int*   dperm2  = (int*)(ws + 59121952);         // N2*4 = 640,000  -> end 59,761,952
  int* bcnt1 = bcnt12, *bcnt2 = bcnt12 + 256;

  // 1: zero bucket counts + both degree histograms (contiguous) in one call
  hipMemsetAsync(bcnt12, 0, 2048 + 512, stream);

  // 2: fused prologue (weight pack + x0->bf16 convert + both bucket histograms)
  k_prologue<<<150 + 625 + NB1 + NB2, 256, 0, stream>>>(
      W1a, R1a, W2a, R2a, W1b, R1b, W2b, R2b, BpA, BpB, BpC, BpD,
      (const float4*)x0, x0bf,
      edge1v + E1, E1, bcnt1, NBK1,
      edge2v + E2, E2, bcnt2, NBK2);

  // 3: dual bucket scan
  k_bscan_dual<<<2, 256, 0, stream>>>(bcnt1, NBK1, E1, bstart1, bcur1,
                                      bcnt2, NBK2, E2, bstart2, bcur2);

  // 4: dual partition (+ up[src] side stream)
  k_bpart_dual<<<NB1 + NB2, 256, 0, stream>>>(
      edge1v, edge1v + E1, (const float2*)pseudo1, up1, E1, bcur1, ebuf1, rbuf1, NBK1, NB1,
      edge2v, edge2v + E2, (const float2*)pseudo2, up2, E2, bcur2, ebuf2, rbuf2, NBK2);

  // 5: dual per-bucket CSR finalize (epk + epkR + per-dst degree histogram)
  k_bcsr_dual<<<NBK1 + NBK2, 256, 0, stream>>>(
      bstart1, ebuf1, rbuf1, epk1, epkR1, off1, dh1, N1, E1, NBK1,
      bstart2, ebuf2, rbuf2, epk2, epkR2, off2, dh2, N2, E2, NBK2);

  // 6: degree-bin prefix (descending) in place
  k_dprep<<<2, 64, 0, stream>>>(dh1, dh2);

  // 7: counting-sort scatter -> dperm (degree-sorted dst order)
  k_dscatter<<<NB1s + NB2s, 256, 0, stream>>>(off1, N1, dh1, dperm1,
                                              off2, N2, dh2, dperm2, NB1s);

  // ---------------- level 1 convs ----------------
  // conv1 gathers x0bf (1.28MB, L2-resident) via epkR1; root via up1[d]
  k_conv<64, 32, false, true,  true ><<<N1 / 16, 256, 0, stream>>>(off1, epkR1, dperm1, x0bf, BpA, b1a, skip1, up1, xcat1, N1, 64);
  k_conv<64, 32, false, false, false><<<N1 / 16, 256, 0, stream>>>(off1, epk1, dperm1, xcat1, BpA, b1a, nullptr, nullptr, x3, N1, 32);
  k_conv<32, 32, false, false, false><<<N1 / 32, 256, 0, stream>>>(off1, epk1, dperm1, x3, BpB, b2a, nullptr, nullptr, h1, N1, 32);

  // ---------------- level 2 convs ----------------
  // conv1 gathers h1 (2.56MB, L2-resident) via epkR2; root via up2[d]; x2 never materialized
  k_conv<32, 16, false, true,  true ><<<N2 / 32, 256, 0, stream>>>(off2, epkR2, dperm2, h1, BpC, b1b, skip2, up2, xcat2, N2, 32);
  k_conv<32, 16, false, false, false><<<N2 / 32, 256, 0, stream>>>(off2, epk2, dperm2, xcat2, BpC, b1b, nullptr, nullptr, x6, N2, 16);
  k_conv<16, 16, true,  false, false><<<N2 / 64, 256, 0, stream>>>(off2, epk2, dperm2, x6, BpD, b2b, nullptr, nullptr, d_out, N2, 16);
}